// Round 14
// baseline (1601.269 us; speedup 1.0000x reference)
//
#include <hip/hip_runtime.h>
#include <hip/hip_bf16.h>
#include <math.h>

#define B_ 4
#define N_ 2048
#define D_ 1024
#define WIN_ 4
#define KTOP 8
#define ALPHA_ 0.3f
#define SCALE_ (1.0f/32.0f)
#define NCH 16          // N_/128 col chunks
#define TROW 36         // ushorts per LDS tile row (72B stride, conflict-free)
#define TPLANE (128 * TROW)
#define INV2048 0.00048828125f

typedef unsigned short ushortT;
typedef _Float16 halfT;
typedef __attribute__((ext_vector_type(8))) _Float16 half8v;  // 8 fp16 (4 VGPR)
typedef __attribute__((ext_vector_type(4))) float f32x4;

__device__ inline ushortT h2u(halfT h){ union{halfT h; ushortT u;} x; x.h=h; return x.u; }
__device__ inline halfT  u2h(ushortT u){ union{halfT h; ushortT u;} x; x.u=u; return x.h; }
__device__ inline float  uh2f(ushortT u){ return (float)u2h(u); }

// ---------------------------------------------------------------------------
// mu f32 -> 2 fp16 planes: a = fp16(x), B = fp16((x - a) * 2048)
// ---------------------------------------------------------------------------
__global__ __launch_bounds__(256)
void split2_mu(const float* __restrict__ src, ushortT* __restrict__ Pa,
               ushortT* __restrict__ Pb)
{
    size_t base = ((size_t)blockIdx.x * 256 + threadIdx.x) * 4;
    float4 v = *reinterpret_cast<const float4*>(&src[base]);
    float vv[4] = {v.x, v.y, v.z, v.w};
    ushort4 pa, pb;
#pragma unroll
    for (int j = 0; j < 4; ++j) {
        float f = vv[j];
        halfT a = (halfT)f;  float r = f - (float)a;
        halfT b = (halfT)(r * 2048.0f);
        ((ushortT*)&pa)[j] = h2u(a); ((ushortT*)&pb)[j] = h2u(b);
    }
    *reinterpret_cast<ushort4*>(&Pa[base]) = pa;
    *reinterpret_cast<ushort4*>(&Pb[base]) = pb;
}

// ---------------------------------------------------------------------------
// W [K][Nn] f32 -> Wt [Nn][K] fp16 (single plane)
// ---------------------------------------------------------------------------
__global__ __launch_bounds__(256)
void transpose_f2h(const float* __restrict__ W, ushortT* __restrict__ Wt,
                   int K, int Nn)
{
    __shared__ float t[32][33];
    const int k0 = blockIdx.x * 32, n0 = blockIdx.y * 32;
    const int tx = threadIdx.x & 31, ty8 = threadIdx.x >> 5;
#pragma unroll
    for (int p = 0; p < 4; ++p) {
        int kk = p * 8 + ty8;
        t[kk][tx] = W[(size_t)(k0 + kk) * Nn + n0 + tx];
    }
    __syncthreads();
#pragma unroll
    for (int p = 0; p < 4; ++p) {
        int nn = p * 8 + ty8;
        Wt[(size_t)(n0 + nn) * K + k0 + tx] = h2u((halfT)t[tx][nn]);
    }
}

// ---------------------------------------------------------------------------
// W [K][Nn] f32 -> 2 transposed fp16 planes [Nn][K]
// ---------------------------------------------------------------------------
__global__ __launch_bounds__(256)
void transpose_split2(const float* __restrict__ W, ushortT* __restrict__ Pa,
                      ushortT* __restrict__ Pb, int K, int Nn)
{
    __shared__ float t[32][33];
    const int k0 = blockIdx.x * 32, n0 = blockIdx.y * 32;
    const int tx = threadIdx.x & 31, ty8 = threadIdx.x >> 5;
#pragma unroll
    for (int p = 0; p < 4; ++p) {
        int kk = p * 8 + ty8;
        t[kk][tx] = W[(size_t)(k0 + kk) * Nn + n0 + tx];
    }
    __syncthreads();
#pragma unroll
    for (int p = 0; p < 4; ++p) {
        int nn = p * 8 + ty8;
        float f = t[tx][nn];
        halfT a = (halfT)f;  float r = f - (float)a;
        halfT b = (halfT)(r * 2048.0f);
        size_t o = (size_t)(n0 + nn) * K + k0 + tx;
        Pa[o] = h2u(a); Pb[o] = h2u(b);
    }
}

// ---------------------------------------------------------------------------
// fp16 MFMA GEMM (proven): 128x128 tile, BK=64, 4 waves, 64x64/wave.
// ---------------------------------------------------------------------------
template<int OUT_HALF>
__global__ __launch_bounds__(256)
void mfma_gemm_h(const ushortT* __restrict__ A, int lda,
                 const ushortT* __restrict__ Bt, int ldb,
                 const float* __restrict__ bias,
                 void* __restrict__ Cout, int ldc, int K)
{
    __shared__ ushortT AsL[128 * 72];
    __shared__ ushortT BsL[128 * 72];
    const int tid = threadIdx.x;
    const int m0 = blockIdx.y * 128;
    const int n0 = blockIdx.x * 128;
    const int w = tid >> 6, lane = tid & 63;
    const int wr = w >> 1, wc = w & 1;

    f32x4 acc[4][4];
#pragma unroll
    for (int mi = 0; mi < 4; ++mi)
#pragma unroll
        for (int ni = 0; ni < 4; ++ni) acc[mi][ni] = (f32x4){0.f, 0.f, 0.f, 0.f};

    for (int k0 = 0; k0 < K; k0 += 64) {
#pragma unroll
        for (int it = 0; it < 4; ++it) {
            int idx = tid + it * 256;        // 0..1023
            int row = idx >> 3, c = idx & 7;
            int4 va = *reinterpret_cast<const int4*>(&A[(size_t)(m0 + row) * lda + k0 + c * 8]);
            *reinterpret_cast<int4*>(&AsL[row * 72 + c * 8]) = va;
            int4 vb = *reinterpret_cast<const int4*>(&Bt[(size_t)(n0 + row) * ldb + k0 + c * 8]);
            *reinterpret_cast<int4*>(&BsL[row * 72 + c * 8]) = vb;
        }
        __syncthreads();
#pragma unroll
        for (int kh = 0; kh < 2; ++kh) {
            const int ko = kh * 32 + (lane >> 4) * 8;
            const int rr = lane & 15;
            half8v af[4], bf[4];
#pragma unroll
            for (int mi = 0; mi < 4; ++mi)
                af[mi] = *reinterpret_cast<const half8v*>(&AsL[(wr * 64 + mi * 16 + rr) * 72 + ko]);
#pragma unroll
            for (int ni = 0; ni < 4; ++ni)
                bf[ni] = *reinterpret_cast<const half8v*>(&BsL[(wc * 64 + ni * 16 + rr) * 72 + ko]);
#pragma unroll
            for (int mi = 0; mi < 4; ++mi)
#pragma unroll
                for (int ni = 0; ni < 4; ++ni)
                    acc[mi][ni] = __builtin_amdgcn_mfma_f32_16x16x32_f16(
                        af[mi], bf[ni], acc[mi][ni], 0, 0, 0);
        }
        __syncthreads();
    }

    const int r4 = (lane >> 4) * 4, cl = lane & 15;
#pragma unroll
    for (int mi = 0; mi < 4; ++mi)
#pragma unroll
        for (int ni = 0; ni < 4; ++ni) {
            int row = m0 + wr * 64 + mi * 16 + r4;
            int col = n0 + wc * 64 + ni * 16 + cl;
            float bb = bias ? bias[col] : 0.f;
#pragma unroll
            for (int r = 0; r < 4; ++r) {
                float v = acc[mi][ni][r] + bb;
                if (OUT_HALF)
                    ((ushortT*)Cout)[(size_t)(row + r) * ldc + col] = h2u((halfT)v);
                else
                    ((float*)Cout)[(size_t)(row + r) * ldc + col] = v;
            }
        }
}

// ---------------------------------------------------------------------------
// Fused pre-act: P is [8192][2048] f32 (cols 0..1023 = self pre-act no bias,
// cols 1024..2047 = neighbor pre-act). S = mean_w silu(P_self + bm1 +
// P_neigh[n-w]), output fp16.
// ---------------------------------------------------------------------------
__global__ __launch_bounds__(256)
void silu_mean(const float* __restrict__ P, const float* __restrict__ bm1,
               ushortT* __restrict__ Sb)
{
    size_t idx4 = (size_t)blockIdx.x * blockDim.x + threadIdx.x;
    size_t base = idx4 << 2;                 // logical [row][1024]
    int row = (int)(base >> 10);
    int col = (int)(base & 1023);
    int n = row & (N_ - 1);
    float4 a = *reinterpret_cast<const float4*>(&P[(size_t)row * 2048 + col]);
    float4 bb = *reinterpret_cast<const float4*>(&bm1[col]);
    a.x += bb.x; a.y += bb.y; a.z += bb.z; a.w += bb.w;
    float sx = 0.f, sy = 0.f, sz = 0.f, sw = 0.f;
#pragma unroll
    for (int w = 1; w <= WIN_; ++w) {
        float xx = a.x, xy = a.y, xz = a.z, xw = a.w;
        if (n >= w) {
            const float4 nb = *reinterpret_cast<const float4*>(
                &P[(size_t)(row - w) * 2048 + 1024 + col]);
            xx += nb.x; xy += nb.y; xz += nb.z; xw += nb.w;
        }
        sx += xx / (1.f + __expf(-xx));
        sy += xy / (1.f + __expf(-xy));
        sz += xz / (1.f + __expf(-xz));
        sw += xw / (1.f + __expf(-xw));
    }
    ushort4 o = {h2u((halfT)(sx * 0.25f)), h2u((halfT)(sy * 0.25f)),
                 h2u((halfT)(sz * 0.25f)), h2u((halfT)(sw * 0.25f))};
    *reinterpret_cast<ushort4*>(&Sb[base]) = o;
}

// ---------------------------------------------------------------------------
__device__ inline void topk_insert(float (&tv)[KTOP], int (&ti)[KTOP], float s, int m)
{
    if ((s > tv[KTOP-1]) || (s == tv[KTOP-1] && m < ti[KTOP-1])) {
        float cs = s; int ci = m;
#pragma unroll
        for (int q = 0; q < KTOP; ++q) {
            bool beats = (cs > tv[q]) || (cs == tv[q] && ci < ti[q]);
            if (beats) { float t0 = tv[q]; int t1 = ti[q];
                         tv[q] = cs; ti[q] = ci; cs = t0; ci = t1; }
        }
    }
}

// ---------------------------------------------------------------------------
// fp16 2-plane 3-product core (R11-proven wave tile 64x32): Tb = base of a
// 4-plane 32-k LDS subtile group. acc0 += Aa*Ba ; acc1 += Aa*BB + AB*Ba.
// ---------------------------------------------------------------------------
#define SPLIT3H_COMPUTE(Tb, wr, wc, lane, acc0, acc1)                           \
    {                                                                           \
        const int rr_ = (lane) & 15, ko_ = ((lane) >> 4) * 8;                   \
        half8v ba0_ = *reinterpret_cast<const half8v*>(                         \
            &Tb[2 * TPLANE + ((wc) * 32 + rr_) * TROW + ko_]);                  \
        half8v ba1_ = *reinterpret_cast<const half8v*>(                         \
            &Tb[2 * TPLANE + ((wc) * 32 + 16 + rr_) * TROW + ko_]);             \
        half8v bB0_ = *reinterpret_cast<const half8v*>(                         \
            &Tb[3 * TPLANE + ((wc) * 32 + rr_) * TROW + ko_]);                  \
        half8v bB1_ = *reinterpret_cast<const half8v*>(                         \
            &Tb[3 * TPLANE + ((wc) * 32 + 16 + rr_) * TROW + ko_]);             \
        _Pragma("unroll")                                                       \
        for (int mi_ = 0; mi_ < 4; ++mi_) {                                     \
            half8v aA_ = *reinterpret_cast<const half8v*>(                      \
                &Tb[0 * TPLANE + ((wr) * 64 + mi_ * 16 + rr_) * TROW + ko_]);   \
            acc0[mi_][0] = __builtin_amdgcn_mfma_f32_16x16x32_f16(              \
                aA_, ba0_, acc0[mi_][0], 0, 0, 0);                              \
            acc0[mi_][1] = __builtin_amdgcn_mfma_f32_16x16x32_f16(              \
                aA_, ba1_, acc0[mi_][1], 0, 0, 0);                              \
            acc1[mi_][0] = __builtin_amdgcn_mfma_f32_16x16x32_f16(              \
                aA_, bB0_, acc1[mi_][0], 0, 0, 0);                              \
            acc1[mi_][1] = __builtin_amdgcn_mfma_f32_16x16x32_f16(              \
                aA_, bB1_, acc1[mi_][1], 0, 0, 0);                              \
        }                                                                       \
        _Pragma("unroll")                                                       \
        for (int mi_ = 0; mi_ < 4; ++mi_) {                                     \
            half8v aB_ = *reinterpret_cast<const half8v*>(                      \
                &Tb[1 * TPLANE + ((wr) * 64 + mi_ * 16 + rr_) * TROW + ko_]);   \
            acc1[mi_][0] = __builtin_amdgcn_mfma_f32_16x16x32_f16(              \
                aB_, ba0_, acc1[mi_][0], 0, 0, 0);                              \
            acc1[mi_][1] = __builtin_amdgcn_mfma_f32_16x16x32_f16(              \
                aB_, ba1_, acc1[mi_][1], 0, 0, 0);                              \
        }                                                                       \
    }

// BK=64 staging: 8 int4/thread (4 planes x 2 k-subtiles). LDS layout:
// subtile kh in {0,1} -> planes [kh*4 .. kh*4+3], each 128 x TROW.
#define S3H_LOAD64(kk)                                                          \
    {                                                                           \
        sg[0][0] = *reinterpret_cast<const int4*>(&P0_[oA_ + (kk)]);            \
        sg[0][1] = *reinterpret_cast<const int4*>(&P0_[oA_ + (kk) + 32]);       \
        sg[1][0] = *reinterpret_cast<const int4*>(&P1_[oA_ + (kk)]);            \
        sg[1][1] = *reinterpret_cast<const int4*>(&P1_[oA_ + (kk) + 32]);       \
        sg[2][0] = *reinterpret_cast<const int4*>(&P2_[oB_ + (kk)]);            \
        sg[2][1] = *reinterpret_cast<const int4*>(&P2_[oB_ + (kk) + 32]);       \
        sg[3][0] = *reinterpret_cast<const int4*>(&P3_[oB_ + (kk)]);            \
        sg[3][1] = *reinterpret_cast<const int4*>(&P3_[oB_ + (kk) + 32]);       \
    }
#define S3H_STORE64()                                                           \
    {                                                                           \
        _Pragma("unroll")                                                       \
        for (int p_ = 0; p_ < 4; ++p_) {                                        \
            *reinterpret_cast<int4*>(&T8[(p_) * TPLANE + ldst]) = sg[p_][0];    \
            *reinterpret_cast<int4*>(&T8[(4 + p_) * TPLANE + ldst]) = sg[p_][1];\
        }                                                                       \
    }

// ---------------------------------------------------------------------------
// gemm_split3h: out = (Aa + AB/2048) @ (Ba + BB/2048)^T + bias, 3 kept
// products. 512 thr, 8 waves, BK=64 (halved barrier count vs R11),
// reg-prefetch, XCD swizzle. Output split into 2 fp16 planes.
// ---------------------------------------------------------------------------
__global__ __launch_bounds__(512, 2)
void gemm_split3h(const ushortT* __restrict__ A0, const ushortT* __restrict__ A1,
                  const ushortT* __restrict__ B0, const ushortT* __restrict__ B1,
                  const float* __restrict__ bias,
                  ushortT* __restrict__ Pa, ushortT* __restrict__ Pb)
{
    __shared__ ushortT T8[8 * TPLANE];     // 73728 B

    int lin = blockIdx.y * 8 + blockIdx.x;                // 0..511
    lin = (lin & 7) * 64 + (lin >> 3);                    // XCD-chunked
    const int m0 = (lin >> 3) * 128;
    const int n0 = (lin & 7) * 128;

    const int tid = threadIdx.x;
    const int wid = tid >> 6, lane = tid & 63;
    const int wr = wid >> 2, wc = wid & 3;
    const int rowL = tid >> 2, cL = tid & 3;

    const ushortT *P0_ = A0, *P1_ = A1, *P2_ = B0, *P3_ = B1;
    const size_t oA_ = (size_t)(m0 + rowL) * D_ + cL * 8;
    const size_t oB_ = (size_t)(n0 + rowL) * D_ + cL * 8;
    const int ldst = rowL * TROW + cL * 8;

    f32x4 acc0[4][2], acc1[4][2];
#pragma unroll
    for (int mi = 0; mi < 4; ++mi) {
        acc0[mi][0] = (f32x4){0,0,0,0}; acc0[mi][1] = (f32x4){0,0,0,0};
        acc1[mi][0] = (f32x4){0,0,0,0}; acc1[mi][1] = (f32x4){0,0,0,0};
    }

    int4 sg[4][2];
    S3H_LOAD64(0)

    for (int ks = 0; ks < 16; ++ks) {
        __syncthreads();
        S3H_STORE64()
        __syncthreads();
        if (ks < 15) S3H_LOAD64((ks + 1) * 64)
        __builtin_amdgcn_s_setprio(1);
        SPLIT3H_COMPUTE(T8, wr, wc, lane, acc0, acc1)
        {
            const ushortT* Tb2 = &T8[4 * TPLANE];
            SPLIT3H_COMPUTE(Tb2, wr, wc, lane, acc0, acc1)
        }
        __builtin_amdgcn_s_setprio(0);
    }

    const int r4 = (lane >> 4) * 4, cl = lane & 15;
#pragma unroll
    for (int mi = 0; mi < 4; ++mi)
#pragma unroll
        for (int ni = 0; ni < 2; ++ni) {
            int col = n0 + wc * 32 + ni * 16 + cl;
            float bb = bias[col];
#pragma unroll
            for (int r = 0; r < 4; ++r) {
                int row = m0 + wr * 64 + mi * 16 + r4 + r;
                float v = acc0[mi][ni][r] + INV2048 * acc1[mi][ni][r] + bb;
                halfT a = (halfT)v;  float r1 = v - (float)a;
                halfT b = (halfT)(r1 * 2048.0f);
                size_t o = (size_t)row * D_ + col;
                Pa[o] = h2u(a); Pb[o] = h2u(b);
            }
        }
}

// ---------------------------------------------------------------------------
// attn_scores_h: fp16 2-plane split scores + mask + pheromone + per-chunk
// top-8. 512 thr, 8 waves, BK=64, reg-prefetch, XCD swizzle.
// ---------------------------------------------------------------------------
__global__ __launch_bounds__(512, 2)
void attn_scores_h(const ushortT* __restrict__ Qa, const ushortT* __restrict__ QB,
                   const ushortT* __restrict__ Ka, const ushortT* __restrict__ KB,
                   const float* __restrict__ pher,
                   float* __restrict__ WV, int* __restrict__ WI)
{
    __shared__ ushortT T8[8 * TPLANE];     // 73728 B
    __shared__ float Ps[128];
    __shared__ float PV[32 * 4 * 8];
    __shared__ int   PI[32 * 4 * 8];
    float* MV = reinterpret_cast<float*>(&T8[0]);                    // [32][128]
    int*   MI = reinterpret_cast<int*>((char*)&T8[0] + 16384);       // [32][128]

    int lin = blockIdx.y * 136 + blockIdx.x;              // 0..543
    lin = (lin & 7) * 68 + (lin >> 3);                    // XCD-chunked, 544=8*68
    const int b = lin / 136;
    const int xy = lin - b * 136;
    int g = 0;
    while ((g + 1) * (g + 2) / 2 <= xy) ++g;
    const int ch = xy - g * (g + 1) / 2;
    const int n0 = g * 128;
    const int m0 = ch * 128;
    const size_t bN = (size_t)b * N_;

    const int tid = threadIdx.x;
    const int wid = tid >> 6, lane = tid & 63;
    const int wr = wid >> 2, wc = wid & 3;
    const int rowL = tid >> 2, cL = tid & 3;

    if (tid < 128) Ps[tid] = pher[bN + m0 + tid];

    const ushortT *P0_ = Qa, *P1_ = QB, *P2_ = Ka, *P3_ = KB;
    const size_t oA_ = (bN + n0 + rowL) * (size_t)D_ + cL * 8;
    const size_t oB_ = (bN + m0 + rowL) * (size_t)D_ + cL * 8;
    const int ldst = rowL * TROW + cL * 8;

    f32x4 acc0[4][2], acc1[4][2];
#pragma unroll
    for (int mi = 0; mi < 4; ++mi) {
        acc0[mi][0] = (f32x4){0,0,0,0}; acc0[mi][1] = (f32x4){0,0,0,0};
        acc1[mi][0] = (f32x4){0,0,0,0}; acc1[mi][1] = (f32x4){0,0,0,0};
    }

    int4 sg[4][2];
    S3H_LOAD64(0)

    for (int ks = 0; ks < 16; ++ks) {
        __syncthreads();
        S3H_STORE64()
        __syncthreads();
        if (ks < 15) S3H_LOAD64((ks + 1) * 64)
        __builtin_amdgcn_s_setprio(1);
        SPLIT3H_COMPUTE(T8, wr, wc, lane, acc0, acc1)
        {
            const ushortT* Tb2 = &T8[4 * TPLANE];
            SPLIT3H_COMPUTE(Tb2, wr, wc, lane, acc0, acc1)
        }
        __builtin_amdgcn_s_setprio(0);
    }

    // ---- fold to per-row top-8: 4 passes of 32 rows (R11-proven) ----
    const int r4 = (lane >> 4) * 4, cl = lane & 15;
    for (int p = 0; p < 4; ++p) {
        __syncthreads();                       // T8/MV consumers done
        if (wr == (p >> 1)) {
#pragma unroll
            for (int mi2 = 0; mi2 < 2; ++mi2) {
                const int mi = (p & 1) * 2 + mi2;
#pragma unroll
                for (int ni = 0; ni < 2; ++ni) {
                    int col = wc * 32 + ni * 16 + cl;
                    int m = m0 + col;
#pragma unroll
                    for (int r = 0; r < 4; ++r) {
                        int rloc = mi2 * 16 + r4 + r;
                        int n = n0 + p * 32 + rloc;
                        bool ok = (m <= n);
                        float sc = acc0[mi][ni][r] + INV2048 * acc1[mi][ni][r];
                        MV[rloc * 128 + col] = ok ? (sc * SCALE_ + ALPHA_ * Ps[col])
                                                  : -INFINITY;
                        MI[rloc * 128 + col] = ok ? m : 0x7fffffff;
                    }
                }
            }
        }
        __syncthreads();
        if (tid < 128) {                       // partial top-8 over a 32-col quarter
            const int row = tid >> 2, q4 = tid & 3;
            float tv[KTOP]; int ti[KTOP];
#pragma unroll
            for (int j = 0; j < KTOP; ++j) { tv[j] = -INFINITY; ti[j] = 0x7fffffff; }
            for (int j = 0; j < 32; ++j) {
                float s2 = MV[row * 128 + q4 * 32 + j];
                if (s2 == -INFINITY) continue;
                topk_insert(tv, ti, s2, MI[row * 128 + q4 * 32 + j]);
            }
#pragma unroll
            for (int j = 0; j < KTOP; ++j) {
                PV[(row * 4 + q4) * 8 + j] = tv[j];
                PI[(row * 4 + q4) * 8 + j] = ti[j];
            }
        }
        __syncthreads();
        if (tid < 32) {                        // merge 4 partials -> chunk top-8
            float tv[KTOP]; int ti[KTOP];
#pragma unroll
            for (int j = 0; j < KTOP; ++j) { tv[j] = -INFINITY; ti[j] = 0x7fffffff; }
            for (int i = 0; i < 32; ++i) {
                float s2 = PV[tid * 32 + i];
                if (s2 == -INFINITY) continue;
                topk_insert(tv, ti, s2, PI[tid * 32 + i]);
            }
            int n = n0 + p * 32 + tid;
            size_t base = ((bN + n) * NCH + ch) * 8;
#pragma unroll
            for (int j = 0; j < KTOP; ++j) { WV[base + j] = tv[j]; WI[base + j] = ti[j]; }
        }
    }
}

// ---------------------------------------------------------------------------
// attn_merge: merge <=16 chunk lists -> top-8 -> softmax -> gather fp16 V ->
// CCb right half (fp16). Grid 2048 blocks, 4 rows each.
// ---------------------------------------------------------------------------
__global__ __launch_bounds__(256)
void attn_merge(const float* __restrict__ WV, const int* __restrict__ WI,
                const ushortT* __restrict__ V, ushortT* __restrict__ CCb)
{
    __shared__ float CV[4][128];
    __shared__ int   CI[4][128];
    __shared__ float Pp[4][KTOP];
    __shared__ int   Pi[4][KTOP];

    const int tid  = threadIdx.x;
    const int wv   = tid >> 6;
    const int lane = tid & 63;
    const int rid  = blockIdx.x * 4 + wv;
    const int b    = rid >> 11;
    const int n    = rid & (N_ - 1);
    const int ncand = ((n >> 7) + 1) * 8;
    const size_t cbase = (size_t)rid * (NCH * 8);

#pragma unroll
    for (int t = 0; t < 2; ++t) {
        int i = lane + t * 64;
        if (i < ncand) { CV[wv][i] = WV[cbase + i]; CI[wv][i] = WI[cbase + i]; }
        else           { CV[wv][i] = -INFINITY;     CI[wv][i] = 0x7fffffff;   }
    }
    __syncthreads();

    if (lane == 0) {
        float tv[KTOP]; int ti[KTOP];
#pragma unroll
        for (int j = 0; j < KTOP; ++j) { tv[j] = -INFINITY; ti[j] = 0x7fffffff; }
        for (int i = 0; i < 128; ++i) {
            float s = CV[wv][i];
            if (s == -INFINITY) continue;
            topk_insert(tv, ti, s, CI[wv][i]);
        }
        float mx = tv[0];
        float e[KTOP]; float sum = 0.f;
#pragma unroll
        for (int j = 0; j < KTOP; ++j) {
            e[j] = (tv[j] == -INFINITY) ? 0.f : __expf(tv[j] - mx);
            sum += e[j];
        }
        float inv = 1.f / sum;
#pragma unroll
        for (int j = 0; j < KTOP; ++j) {
            Pp[wv][j] = e[j] * inv;
            Pi[wv][j] = (tv[j] == -INFINITY) ? 0 : ti[j];
        }
    }
    __syncthreads();

    const size_t vbase = (size_t)b * N_ * D_;
#pragma unroll
    for (int it = 0; it < 2; ++it) {
        int c8 = (it * 64 + lane) * 8;
        float o[8];
#pragma unroll
        for (int u = 0; u < 8; ++u) o[u] = 0.f;
#pragma unroll
        for (int j = 0; j < KTOP; ++j) {
            float p = Pp[wv][j];
            ushort4 v0 = *reinterpret_cast<const ushort4*>(
                &V[vbase + (size_t)Pi[wv][j] * D_ + c8]);
            ushort4 v1 = *reinterpret_cast<const ushort4*>(
                &V[vbase + (size_t)Pi[wv][j] * D_ + c8 + 4]);
            o[0] = fmaf(p, uh2f(v0.x), o[0]); o[1] = fmaf(p, uh2f(v0.y), o[1]);
            o[2] = fmaf(p, uh2f(v0.z), o[2]); o[3] = fmaf(p, uh2f(v0.w), o[3]);
            o[4] = fmaf(p, uh2f(v1.x), o[4]); o[5] = fmaf(p, uh2f(v1.y), o[5]);
            o[6] = fmaf(p, uh2f(v1.z), o[6]); o[7] = fmaf(p, uh2f(v1.w), o[7]);
        }
        ushort4 ob0 = {h2u((halfT)o[0]), h2u((halfT)o[1]), h2u((halfT)o[2]), h2u((halfT)o[3])};
        ushort4 ob1 = {h2u((halfT)o[4]), h2u((halfT)o[5]), h2u((halfT)o[6]), h2u((halfT)o[7])};
        *reinterpret_cast<ushort4*>(&CCb[(size_t)rid * 2048 + 1024 + c8]) = ob0;
        *reinterpret_cast<ushort4*>(&CCb[(size_t)rid * 2048 + 1024 + c8 + 4]) = ob1;
    }
}

// ---------------------------------------------------------------------------
extern "C" void kernel_launch(void* const* d_in, const int* in_sizes, int n_in,
                              void* d_out, int out_size, void* d_ws, size_t ws_size,
                              hipStream_t stream)
{
    const float* mu   = (const float*)d_in[0];
    const float* pher = (const float*)d_in[1];
    const float* Wq   = (const float*)d_in[2];
    const float* bq   = (const float*)d_in[3];
    const float* Wk   = (const float*)d_in[4];
    const float* bk   = (const float*)d_in[5];
    const float* Wv   = (const float*)d_in[6];
    const float* bv   = (const float*)d_in[7];
    const float* Wm1  = (const float*)d_in[8];
    const float* bm1  = (const float*)d_in[9];
    const float* Wm2  = (const float*)d_in[10];
    const float* bm2  = (const float*)d_in[11];
    const float* Wo   = (const float*)d_in[12];
    const float* bo   = (const float*)d_in[13];
    float* out = (float*)d_out;
    float* ws  = (float*)d_ws;

    const size_t SZ  = (size_t)B_ * N_ * D_;    // 8388608 floats
    const size_t MEG = 1024 * 1024;             // floats
    const int M = B_ * N_;                      // 8192

    // ---- workspace map (float units), as R13 ----
    ushortT* CCb  = (ushortT*)ws;                         // [8192][2048] fp16
    float*   PF   = ws + SZ;                              // fused pre-act [8192][2048] f32
    ushortT* Qa   = (ushortT*)(ws + SZ);                  // overlay after silu
    ushortT* QB   = Qa + SZ;
    ushortT* Ka   = (ushortT*)(ws + 2 * SZ);
    ushortT* KB   = Ka + SZ;
    ushortT* mu_a = (ushortT*)(ws + 3 * SZ);              // fp16 plane (SZ ushorts)
    ushortT* mu_B = mu_a + SZ;                            // scaled residual plane
    ushortT* Sb   = (ushortT*)(ws + 4 * SZ);              // fp16 S; dead after local gemm
    float*   WVb  = (float*)(ws + 4 * SZ);                // overlay Sb after local gemm
    int*     WIb  = (int*)(WVb + MEG);
    ushortT* Vb16 = (ushortT*)(ws + 4 * SZ + 2 * MEG);    // fp16 V (SZ ushorts)
    ushortT* U    = (ushortT*)(ws + 4 * SZ + 2 * MEG + SZ / 2);   // weights (10M ush)
    ushortT* WtF  = U;                   // [2048][1024] fused Wm1^T = 2M ush
    ushortT* Wt_m2 = U + 2 * MEG;        // [1024][1024] = 1M ush
    ushortT* Wt_v  = U + 3 * MEG;        // 1M ush
    ushortT* WqT_a = U + 4 * MEG;        ushortT* WqT_B = U + 5 * MEG;
    ushortT* WkT_a = U + 6 * MEG;        ushortT* WkT_B = U + 7 * MEG;
    ushortT* Wt_o  = U + 8 * MEG;        // [1024][2048] = 2M ush

    dim3 blk256(256), blk512(512);
    dim3 gD(8, 64);

    // 1. mu -> 2 fp16 planes
    hipLaunchKernelGGL(split2_mu, dim3(SZ / 8 / 128), blk256, 0, stream, mu, mu_a, mu_B);
    // 2. weight transposes. WtF: rows 0..1023 = Wm1_top^T, rows 1024..2047 = Wm1_bot^T
    hipLaunchKernelGGL(transpose_f2h, dim3(32, 32), blk256, 0, stream, Wm1, WtF, 1024, 1024);
    hipLaunchKernelGGL(transpose_f2h, dim3(32, 32), blk256, 0, stream,
                       Wm1 + (size_t)1024 * 1024, WtF + (size_t)1024 * 1024, 1024, 1024);
    hipLaunchKernelGGL(transpose_f2h, dim3(32, 32), blk256, 0, stream, Wm2, Wt_m2, 1024, 1024);
    hipLaunchKernelGGL(transpose_f2h, dim3(32, 32), blk256, 0, stream, Wv, Wt_v, 1024, 1024);
    hipLaunchKernelGGL(transpose_f2h, dim3(64, 32), blk256, 0, stream, Wo, Wt_o, 2048, 1024);
    hipLaunchKernelGGL(transpose_split2, dim3(32, 32), blk256, 0, stream,
                       Wq, WqT_a, WqT_B, 1024, 1024);
    hipLaunchKernelGGL(transpose_split2, dim3(32, 32), blk256, 0, stream,
                       Wk, WkT_a, WkT_B, 1024, 1024);
    // 3. FUSED pre-acts: PF[8192][2048] = mu @ [Wm1_top | Wm1_bot] (no bias)
    hipLaunchKernelGGL((mfma_gemm_h<0>), dim3(16, 64), blk256, 0, stream,
                       mu_a, D_, WtF, D_, (const float*)nullptr, (void*)PF, 2 * D_, D_);
    // 4. silu-mean (adds bm1 inside) -> Sb (fp16)
    hipLaunchKernelGGL(silu_mean, dim3(SZ / 4 / 256), blk256, 0, stream, PF, bm1, Sb);
    // 5. local msgs -> CCb left half (fp16)
    hipLaunchKernelGGL((mfma_gemm_h<1>), gD, blk256, 0, stream,
                       Sb, D_, Wt_m2, D_, bm2, (void*)CCb, 2 * D_, D_);
    // 6. V -> fp16
    hipLaunchKernelGGL((mfma_gemm_h<1>), gD, blk256, 0, stream,
                       mu_a, D_, Wt_v, D_, bv, (void*)Vb16, D_, D_);
    // 7-8. Q/K projections (fp16 split-MFMA, f32-equivalent) -> 2 planes each
    hipLaunchKernelGGL(gemm_split3h, gD, blk512, 0, stream,
                       mu_a, mu_B, WqT_a, WqT_B, bq, Qa, QB);
    hipLaunchKernelGGL(gemm_split3h, gD, blk512, 0, stream,
                       mu_a, mu_B, WkT_a, WkT_B, bk, Ka, KB);
    // 9. scores + per-chunk top-8
    hipLaunchKernelGGL(attn_scores_h, dim3(136, B_), blk512, 0, stream,
                       Qa, QB, Ka, KB, pher, WVb, WIb);
    // 10. merge + softmax + V gather -> CCb right half
    hipLaunchKernelGGL(attn_merge, dim3(M / 4), blk256, 0, stream, WVb, WIb, Vb16, CCb);
    // 11. out = CCb @ Wo + bo (fp16 MFMA, K=2048, f32 out)
    hipLaunchKernelGGL((mfma_gemm_h<0>), gD, blk256, 0, stream,
                       CCb, 2 * D_, Wt_o, 2048, bo, (void*)out, D_, 2 * D_);

    (void)in_sizes; (void)n_in; (void)out_size; (void)ws_size;
}

// Round 15
// 757.538 us; speedup vs baseline: 2.1138x; 2.1138x over previous
//
#include <hip/hip_runtime.h>
#include <hip/hip_bf16.h>
#include <math.h>

#define B_ 4
#define N_ 2048
#define D_ 1024
#define WIN_ 4
#define KTOP 8
#define ALPHA_ 0.3f
#define SCALE_ (1.0f/32.0f)
#define NCH 16          // N_/128 col chunks
#define INV2048 0.00048828125f

typedef unsigned short ushortT;
typedef _Float16 halfT;
typedef __attribute__((ext_vector_type(8))) _Float16 half8v;  // 8 fp16 (4 VGPR)
typedef __attribute__((ext_vector_type(4))) float f32x4;

__device__ inline ushortT h2u(halfT h){ union{halfT h; ushortT u;} x; x.h=h; return x.u; }
__device__ inline halfT  u2h(ushortT u){ union{halfT h; ushortT u;} x; x.u=u; return x.h; }
__device__ inline float  uh2f(ushortT u){ return (float)u2h(u); }

// async global->LDS, 16B per lane (dest = wave-uniform base + lane*16)
__device__ __forceinline__ void gll16(const ushortT* g, ushortT* l) {
    __builtin_amdgcn_global_load_lds(
        (const __attribute__((address_space(1))) void*)g,
        (__attribute__((address_space(3))) void*)l, 16, 0, 0);
}

// ---------------------------------------------------------------------------
// mu f32 -> 2 fp16 planes: a = fp16(x), B = fp16((x - a) * 2048)
// ---------------------------------------------------------------------------
__global__ __launch_bounds__(256)
void split2_mu(const float* __restrict__ src, ushortT* __restrict__ Pa,
               ushortT* __restrict__ Pb)
{
    size_t base = ((size_t)blockIdx.x * 256 + threadIdx.x) * 4;
    float4 v = *reinterpret_cast<const float4*>(&src[base]);
    float vv[4] = {v.x, v.y, v.z, v.w};
    ushort4 pa, pb;
#pragma unroll
    for (int j = 0; j < 4; ++j) {
        float f = vv[j];
        halfT a = (halfT)f;  float r = f - (float)a;
        halfT b = (halfT)(r * 2048.0f);
        ((ushortT*)&pa)[j] = h2u(a); ((ushortT*)&pb)[j] = h2u(b);
    }
    *reinterpret_cast<ushort4*>(&Pa[base]) = pa;
    *reinterpret_cast<ushort4*>(&Pb[base]) = pb;
}

// ---------------------------------------------------------------------------
// W [K][Nn] f32 -> Wt [Nn][K] fp16 (single plane)
// ---------------------------------------------------------------------------
__global__ __launch_bounds__(256)
void transpose_f2h(const float* __restrict__ W, ushortT* __restrict__ Wt,
                   int K, int Nn)
{
    __shared__ float t[32][33];
    const int k0 = blockIdx.x * 32, n0 = blockIdx.y * 32;
    const int tx = threadIdx.x & 31, ty8 = threadIdx.x >> 5;
#pragma unroll
    for (int p = 0; p < 4; ++p) {
        int kk = p * 8 + ty8;
        t[kk][tx] = W[(size_t)(k0 + kk) * Nn + n0 + tx];
    }
    __syncthreads();
#pragma unroll
    for (int p = 0; p < 4; ++p) {
        int nn = p * 8 + ty8;
        Wt[(size_t)(n0 + nn) * K + k0 + tx] = h2u((halfT)t[tx][nn]);
    }
}

// ---------------------------------------------------------------------------
// W [K][Nn] f32 -> 2 transposed fp16 planes [Nn][K]
// ---------------------------------------------------------------------------
__global__ __launch_bounds__(256)
void transpose_split2(const float* __restrict__ W, ushortT* __restrict__ Pa,
                      ushortT* __restrict__ Pb, int K, int Nn)
{
    __shared__ float t[32][33];
    const int k0 = blockIdx.x * 32, n0 = blockIdx.y * 32;
    const int tx = threadIdx.x & 31, ty8 = threadIdx.x >> 5;
#pragma unroll
    for (int p = 0; p < 4; ++p) {
        int kk = p * 8 + ty8;
        t[kk][tx] = W[(size_t)(k0 + kk) * Nn + n0 + tx];
    }
    __syncthreads();
#pragma unroll
    for (int p = 0; p < 4; ++p) {
        int nn = p * 8 + ty8;
        float f = t[tx][nn];
        halfT a = (halfT)f;  float r = f - (float)a;
        halfT b = (halfT)(r * 2048.0f);
        size_t o = (size_t)(n0 + nn) * K + k0 + tx;
        Pa[o] = h2u(a); Pb[o] = h2u(b);
    }
}

// ---------------------------------------------------------------------------
// fp16 MFMA GEMM (proven): 128x128 tile, BK=64, 4 waves, 64x64/wave.
// ---------------------------------------------------------------------------
template<int OUT_HALF>
__global__ __launch_bounds__(256)
void mfma_gemm_h(const ushortT* __restrict__ A, int lda,
                 const ushortT* __restrict__ Bt, int ldb,
                 const float* __restrict__ bias,
                 void* __restrict__ Cout, int ldc, int K)
{
    __shared__ ushortT AsL[128 * 72];
    __shared__ ushortT BsL[128 * 72];
    const int tid = threadIdx.x;
    const int m0 = blockIdx.y * 128;
    const int n0 = blockIdx.x * 128;
    const int w = tid >> 6, lane = tid & 63;
    const int wr = w >> 1, wc = w & 1;

    f32x4 acc[4][4];
#pragma unroll
    for (int mi = 0; mi < 4; ++mi)
#pragma unroll
        for (int ni = 0; ni < 4; ++ni) acc[mi][ni] = (f32x4){0.f, 0.f, 0.f, 0.f};

    for (int k0 = 0; k0 < K; k0 += 64) {
#pragma unroll
        for (int it = 0; it < 4; ++it) {
            int idx = tid + it * 256;        // 0..1023
            int row = idx >> 3, c = idx & 7;
            int4 va = *reinterpret_cast<const int4*>(&A[(size_t)(m0 + row) * lda + k0 + c * 8]);
            *reinterpret_cast<int4*>(&AsL[row * 72 + c * 8]) = va;
            int4 vb = *reinterpret_cast<const int4*>(&Bt[(size_t)(n0 + row) * ldb + k0 + c * 8]);
            *reinterpret_cast<int4*>(&BsL[row * 72 + c * 8]) = vb;
        }
        __syncthreads();
#pragma unroll
        for (int kh = 0; kh < 2; ++kh) {
            const int ko = kh * 32 + (lane >> 4) * 8;
            const int rr = lane & 15;
            half8v af[4], bf[4];
#pragma unroll
            for (int mi = 0; mi < 4; ++mi)
                af[mi] = *reinterpret_cast<const half8v*>(&AsL[(wr * 64 + mi * 16 + rr) * 72 + ko]);
#pragma unroll
            for (int ni = 0; ni < 4; ++ni)
                bf[ni] = *reinterpret_cast<const half8v*>(&BsL[(wc * 64 + ni * 16 + rr) * 72 + ko]);
#pragma unroll
            for (int mi = 0; mi < 4; ++mi)
#pragma unroll
                for (int ni = 0; ni < 4; ++ni)
                    acc[mi][ni] = __builtin_amdgcn_mfma_f32_16x16x32_f16(
                        af[mi], bf[ni], acc[mi][ni], 0, 0, 0);
        }
        __syncthreads();
    }

    const int r4 = (lane >> 4) * 4, cl = lane & 15;
#pragma unroll
    for (int mi = 0; mi < 4; ++mi)
#pragma unroll
        for (int ni = 0; ni < 4; ++ni) {
            int row = m0 + wr * 64 + mi * 16 + r4;
            int col = n0 + wc * 64 + ni * 16 + cl;
            float bb = bias ? bias[col] : 0.f;
#pragma unroll
            for (int r = 0; r < 4; ++r) {
                float v = acc[mi][ni][r] + bb;
                if (OUT_HALF)
                    ((ushortT*)Cout)[(size_t)(row + r) * ldc + col] = h2u((halfT)v);
                else
                    ((float*)Cout)[(size_t)(row + r) * ldc + col] = v;
            }
        }
}

// ---------------------------------------------------------------------------
// Fused pre-act: P is [8192][2048] f32 (cols 0..1023 = self pre-act no bias,
// cols 1024..2047 = neighbor pre-act). S = mean_w silu(P_self + bm1 +
// P_neigh[n-w]), output fp16.
// ---------------------------------------------------------------------------
__global__ __launch_bounds__(256)
void silu_mean(const float* __restrict__ P, const float* __restrict__ bm1,
               ushortT* __restrict__ Sb)
{
    size_t idx4 = (size_t)blockIdx.x * blockDim.x + threadIdx.x;
    size_t base = idx4 << 2;                 // logical [row][1024]
    int row = (int)(base >> 10);
    int col = (int)(base & 1023);
    int n = row & (N_ - 1);
    float4 a = *reinterpret_cast<const float4*>(&P[(size_t)row * 2048 + col]);
    float4 bb = *reinterpret_cast<const float4*>(&bm1[col]);
    a.x += bb.x; a.y += bb.y; a.z += bb.z; a.w += bb.w;
    float sx = 0.f, sy = 0.f, sz = 0.f, sw = 0.f;
#pragma unroll
    for (int w = 1; w <= WIN_; ++w) {
        float xx = a.x, xy = a.y, xz = a.z, xw = a.w;
        if (n >= w) {
            const float4 nb = *reinterpret_cast<const float4*>(
                &P[(size_t)(row - w) * 2048 + 1024 + col]);
            xx += nb.x; xy += nb.y; xz += nb.z; xw += nb.w;
        }
        sx += xx / (1.f + __expf(-xx));
        sy += xy / (1.f + __expf(-xy));
        sz += xz / (1.f + __expf(-xz));
        sw += xw / (1.f + __expf(-xw));
    }
    ushort4 o = {h2u((halfT)(sx * 0.25f)), h2u((halfT)(sy * 0.25f)),
                 h2u((halfT)(sz * 0.25f)), h2u((halfT)(sw * 0.25f))};
    *reinterpret_cast<ushort4*>(&Sb[base]) = o;
}

// ---------------------------------------------------------------------------
__device__ inline void topk_insert(float (&tv)[KTOP], int (&ti)[KTOP], float s, int m)
{
    if ((s > tv[KTOP-1]) || (s == tv[KTOP-1] && m < ti[KTOP-1])) {
        float cs = s; int ci = m;
#pragma unroll
        for (int q = 0; q < KTOP; ++q) {
            bool beats = (cs > tv[q]) || (cs == tv[q] && ci < ti[q]);
            if (beats) { float t0 = tv[q]; int t1 = ti[q];
                         tv[q] = cs; ti[q] = ci; cs = t0; ci = t1; }
        }
    }
}

// ---------------------------------------------------------------------------
// fp16 2-plane 3-product core on gload_lds layout: plane = 128 rows x 32
// ushorts LINEAR (64B rows); data chunk q of row R stored at slot
// q ^ ((R>>1)&3) (source-side swizzle) -> 2-way-aliased ds_read (free).
// Wave tile 64x32 (wr in {0,1}, wc in {0..3}). acc0 += Aa*Ba ;
// acc1 += Aa*BB + AB*Ba. MFMA order identical to R11 -> bit-identical.
// ---------------------------------------------------------------------------
#define SPLIT3H_COMPUTE(Tb, wr, wc, lane, acc0, acc1)                           \
    {                                                                           \
        const int rr_ = (lane) & 15, q_ = (lane) >> 4;                          \
        const int Rb0_ = (wc) * 32 + rr_;                                       \
        const int Rb1_ = Rb0_ + 16;                                             \
        half8v ba0_ = *reinterpret_cast<const half8v*>(                         \
            &Tb[2 * 4096 + Rb0_ * 32 + ((q_ ^ ((Rb0_ >> 1) & 3)) << 3)]);       \
        half8v ba1_ = *reinterpret_cast<const half8v*>(                         \
            &Tb[2 * 4096 + Rb1_ * 32 + ((q_ ^ ((Rb1_ >> 1) & 3)) << 3)]);       \
        half8v bB0_ = *reinterpret_cast<const half8v*>(                         \
            &Tb[3 * 4096 + Rb0_ * 32 + ((q_ ^ ((Rb0_ >> 1) & 3)) << 3)]);       \
        half8v bB1_ = *reinterpret_cast<const half8v*>(                         \
            &Tb[3 * 4096 + Rb1_ * 32 + ((q_ ^ ((Rb1_ >> 1) & 3)) << 3)]);       \
        _Pragma("unroll")                                                       \
        for (int mi_ = 0; mi_ < 4; ++mi_) {                                     \
            const int Ra_ = (wr) * 64 + mi_ * 16 + rr_;                         \
            const int sw_ = (q_ ^ ((Ra_ >> 1) & 3)) << 3;                       \
            half8v aA_ = *reinterpret_cast<const half8v*>(&Tb[Ra_ * 32 + sw_]); \
            acc0[mi_][0] = __builtin_amdgcn_mfma_f32_16x16x32_f16(              \
                aA_, ba0_, acc0[mi_][0], 0, 0, 0);                              \
            acc0[mi_][1] = __builtin_amdgcn_mfma_f32_16x16x32_f16(              \
                aA_, ba1_, acc0[mi_][1], 0, 0, 0);                              \
            acc1[mi_][0] = __builtin_amdgcn_mfma_f32_16x16x32_f16(              \
                aA_, bB0_, acc1[mi_][0], 0, 0, 0);                              \
            acc1[mi_][1] = __builtin_amdgcn_mfma_f32_16x16x32_f16(              \
                aA_, bB1_, acc1[mi_][1], 0, 0, 0);                              \
        }                                                                       \
        _Pragma("unroll")                                                       \
        for (int mi_ = 0; mi_ < 4; ++mi_) {                                     \
            const int Ra_ = (wr) * 64 + mi_ * 16 + rr_;                         \
            const int sw_ = (q_ ^ ((Ra_ >> 1) & 3)) << 3;                       \
            half8v aB_ = *reinterpret_cast<const half8v*>(                      \
                &Tb[4096 + Ra_ * 32 + sw_]);                                    \
            acc1[mi_][0] = __builtin_amdgcn_mfma_f32_16x16x32_f16(              \
                aB_, ba0_, acc1[mi_][0], 0, 0, 0);                              \
            acc1[mi_][1] = __builtin_amdgcn_mfma_f32_16x16x32_f16(              \
                aB_, ba1_, acc1[mi_][1], 0, 0, 0);                              \
        }                                                                       \
    }

// stage one 32-k tile of one plane (this wave's half): 4 x gll16 (1KB each)
#define STAGE4(lb, koff)                                                        \
    {                                                                           \
        gll16(gp + goff + (koff), lb);                                          \
        gll16(gp + goff + (koff) + 16 * D_, (lb) + 512);                        \
        gll16(gp + goff + (koff) + 32 * D_, (lb) + 1024);                       \
        gll16(gp + goff + (koff) + 48 * D_, (lb) + 1536);                       \
    }

// ---------------------------------------------------------------------------
// gemm_split3h: out = (Aa + AB/2048) @ (Ba + BB/2048)^T + bias, 3 kept
// products. 512 thr, 8 waves, BK=32, global_load_lds double-buffer,
// ONE barrier per K-step. XCD swizzle. Output split into 2 fp16 planes.
// ---------------------------------------------------------------------------
__global__ __launch_bounds__(512, 2)
void gemm_split3h(const ushortT* __restrict__ A0, const ushortT* __restrict__ A1,
                  const ushortT* __restrict__ B0, const ushortT* __restrict__ B1,
                  const float* __restrict__ bias,
                  ushortT* __restrict__ Pa, ushortT* __restrict__ Pb)
{
    __shared__ ushortT TT[2][16384];   // 2 x 32KB, linear plane = 128x32 ush

    int lin = blockIdx.y * 8 + blockIdx.x;                // 0..511
    lin = (lin & 7) * 64 + (lin >> 3);                    // XCD-chunked
    const int m0 = (lin >> 3) * 128;
    const int n0 = (lin & 7) * 128;

    const int tid = threadIdx.x;
    const int wid = tid >> 6, lane = tid & 63;
    const int wr = wid >> 2, wc = wid & 3;

    // staging setup: wave wid covers plane pl = wid>>1, rows half hb
    const int pl = wid >> 1;
    const int hb = (wid & 1) * 64;
    const ushortT* gp = (pl == 0) ? A0 : (pl == 1) ? A1 : (pl == 2) ? B0 : B1;
    const int rbase = (pl < 2 ? m0 : n0) + hb + (lane >> 2);
    const int cg8 = ((lane & 3) ^ ((lane >> 3) & 3)) << 3;   // src-side swizzle
    const size_t goff = (size_t)rbase * D_ + cg8;
    ushortT* lb0 = &TT[0][pl * 4096 + hb * 32];
    ushortT* lb1 = &TT[1][pl * 4096 + hb * 32];

    f32x4 acc0[4][2], acc1[4][2];
#pragma unroll
    for (int mi = 0; mi < 4; ++mi) {
        acc0[mi][0] = (f32x4){0,0,0,0}; acc0[mi][1] = (f32x4){0,0,0,0};
        acc1[mi][0] = (f32x4){0,0,0,0}; acc1[mi][1] = (f32x4){0,0,0,0};
    }

    STAGE4(lb0, 0)
    __syncthreads();           // drain vmcnt + barrier: buf0 ready

    int cur = 0;
    for (int ks = 0; ks < 32; ++ks) {
        if (ks < 31) {
            ushortT* lb = cur ? lb0 : lb1;
            STAGE4(lb, (size_t)(ks + 1) * 32)
        }
        const ushortT* Tb = &TT[cur][0];
        __builtin_amdgcn_s_setprio(1);
        SPLIT3H_COMPUTE(Tb, wr, wc, lane, acc0, acc1)
        __builtin_amdgcn_s_setprio(0);
        __syncthreads();       // drain my loads + all waves done reading cur
        cur ^= 1;
    }

    const int r4 = (lane >> 4) * 4, cl = lane & 15;
#pragma unroll
    for (int mi = 0; mi < 4; ++mi)
#pragma unroll
        for (int ni = 0; ni < 2; ++ni) {
            int col = n0 + wc * 32 + ni * 16 + cl;
            float bb = bias[col];
#pragma unroll
            for (int r = 0; r < 4; ++r) {
                int row = m0 + wr * 64 + mi * 16 + r4 + r;
                float v = acc0[mi][ni][r] + INV2048 * acc1[mi][ni][r] + bb;
                halfT a = (halfT)v;  float r1 = v - (float)a;
                halfT b = (halfT)(r1 * 2048.0f);
                size_t o = (size_t)row * D_ + col;
                Pa[o] = h2u(a); Pb[o] = h2u(b);
            }
        }
}

// ---------------------------------------------------------------------------
// attn_scores_h: fp16 2-plane split scores + mask + pheromone + per-chunk
// top-8. 512 thr, 8 waves, BK=32, global_load_lds dbuf, 1 barrier/K-step.
// ---------------------------------------------------------------------------
__global__ __launch_bounds__(512, 2)
void attn_scores_h(const ushortT* __restrict__ Qa, const ushortT* __restrict__ QB,
                   const ushortT* __restrict__ Ka, const ushortT* __restrict__ KB,
                   const float* __restrict__ pher,
                   float* __restrict__ WV, int* __restrict__ WI)
{
    __shared__ ushortT TT[2][16384];   // 2 x 32KB
    __shared__ float Ps[128];
    __shared__ float PV[32 * 4 * 8];
    __shared__ int   PI[32 * 4 * 8];
    float* MV = reinterpret_cast<float*>(&TT[0][0]);                 // [32][128]
    int*   MI = reinterpret_cast<int*>((char*)&TT[0][0] + 16384);    // [32][128]

    int lin = blockIdx.y * 136 + blockIdx.x;              // 0..543
    lin = (lin & 7) * 68 + (lin >> 3);                    // XCD-chunked, 544=8*68
    const int b = lin / 136;
    const int xy = lin - b * 136;
    int g = 0;
    while ((g + 1) * (g + 2) / 2 <= xy) ++g;
    const int ch = xy - g * (g + 1) / 2;
    const int n0 = g * 128;
    const int m0 = ch * 128;
    const size_t bN = (size_t)b * N_;

    const int tid = threadIdx.x;
    const int wid = tid >> 6, lane = tid & 63;
    const int wr = wid >> 2, wc = wid & 3;

    if (tid < 128) Ps[tid] = pher[bN + m0 + tid];

    // staging setup
    const int pl = wid >> 1;
    const int hb = (wid & 1) * 64;
    const ushortT* gp = (pl == 0) ? Qa : (pl == 1) ? QB : (pl == 2) ? Ka : KB;
    const size_t rbase = bN + (pl < 2 ? n0 : m0) + hb + (lane >> 2);
    const int cg8 = ((lane & 3) ^ ((lane >> 3) & 3)) << 3;
    const size_t goff = rbase * (size_t)D_ + cg8;
    ushortT* lb0 = &TT[0][pl * 4096 + hb * 32];
    ushortT* lb1 = &TT[1][pl * 4096 + hb * 32];

    f32x4 acc0[4][2], acc1[4][2];
#pragma unroll
    for (int mi = 0; mi < 4; ++mi) {
        acc0[mi][0] = (f32x4){0,0,0,0}; acc0[mi][1] = (f32x4){0,0,0,0};
        acc1[mi][0] = (f32x4){0,0,0,0}; acc1[mi][1] = (f32x4){0,0,0,0};
    }

    STAGE4(lb0, 0)
    __syncthreads();

    int cur = 0;
    for (int ks = 0; ks < 32; ++ks) {
        if (ks < 31) {
            ushortT* lb = cur ? lb0 : lb1;
            STAGE4(lb, (size_t)(ks + 1) * 32)
        }
        const ushortT* Tb = &TT[cur][0];
        __builtin_amdgcn_s_setprio(1);
        SPLIT3H_COMPUTE(Tb, wr, wc, lane, acc0, acc1)
        __builtin_amdgcn_s_setprio(0);
        __syncthreads();
        cur ^= 1;
    }

    // ---- fold to per-row top-8: 4 passes of 32 rows (R11-proven) ----
    const int r4 = (lane >> 4) * 4, cl = lane & 15;
    for (int p = 0; p < 4; ++p) {
        __syncthreads();                       // TT/MV consumers done
        if (wr == (p >> 1)) {
#pragma unroll
            for (int mi2 = 0; mi2 < 2; ++mi2) {
                const int mi = (p & 1) * 2 + mi2;
#pragma unroll
                for (int ni = 0; ni < 2; ++ni) {
                    int col = wc * 32 + ni * 16 + cl;
                    int m = m0 + col;
#pragma unroll
                    for (int r = 0; r < 4; ++r) {
                        int rloc = mi2 * 16 + r4 + r;
                        int n = n0 + p * 32 + rloc;
                        bool ok = (m <= n);
                        float sc = acc0[mi][ni][r] + INV2048 * acc1[mi][ni][r];
                        MV[rloc * 128 + col] = ok ? (sc * SCALE_ + ALPHA_ * Ps[col])
                                                  : -INFINITY;
                        MI[rloc * 128 + col] = ok ? m : 0x7fffffff;
                    }
                }
            }
        }
        __syncthreads();
        if (tid < 128) {                       // partial top-8 over a 32-col quarter
            const int row = tid >> 2, q4 = tid & 3;
            float tv[KTOP]; int ti[KTOP];
#pragma unroll
            for (int j = 0; j < KTOP; ++j) { tv[j] = -INFINITY; ti[j] = 0x7fffffff; }
            for (int j = 0; j < 32; ++j) {
                float s2 = MV[row * 128 + q4 * 32 + j];
                if (s2 == -INFINITY) continue;
                topk_insert(tv, ti, s2, MI[row * 128 + q4 * 32 + j]);
            }
#pragma unroll
            for (int j = 0; j < KTOP; ++j) {
                PV[(row * 4 + q4) * 8 + j] = tv[j];
                PI[(row * 4 + q4) * 8 + j] = ti[j];
            }
        }
        __syncthreads();
        if (tid < 32) {                        // merge 4 partials -> chunk top-8
            float tv[KTOP]; int ti[KTOP];
#pragma unroll
            for (int j = 0; j < KTOP; ++j) { tv[j] = -INFINITY; ti[j] = 0x7fffffff; }
            for (int i = 0; i < 32; ++i) {
                float s2 = PV[tid * 32 + i];
                if (s2 == -INFINITY) continue;
                topk_insert(tv, ti, s2, PI[tid * 32 + i]);
            }
            int n = n0 + p * 32 + tid;
            size_t base = ((bN + n) * NCH + ch) * 8;
#pragma unroll
            for (int j = 0; j < KTOP; ++j) { WV[base + j] = tv[j]; WI[base + j] = ti[j]; }
        }
    }
}

// ---------------------------------------------------------------------------
// attn_merge: merge <=16 chunk lists -> top-8 -> softmax -> gather fp16 V ->
// CCb right half (fp16). Grid 2048 blocks, 4 rows each.
// ---------------------------------------------------------------------------
__global__ __launch_bounds__(256)
void attn_merge(const float* __restrict__ WV, const int* __restrict__ WI,
                const ushortT* __restrict__ V, ushortT* __restrict__ CCb)
{
    __shared__ float CV[4][128];
    __shared__ int   CI[4][128];
    __shared__ float Pp[4][KTOP];
    __shared__ int   Pi[4][KTOP];

    const int tid  = threadIdx.x;
    const int wv   = tid >> 6;
    const int lane = tid & 63;
    const int rid  = blockIdx.x * 4 + wv;
    const int b    = rid >> 11;
    const int n    = rid & (N_ - 1);
    const int ncand = ((n >> 7) + 1) * 8;
    const size_t cbase = (size_t)rid * (NCH * 8);

#pragma unroll
    for (int t = 0; t < 2; ++t) {
        int i = lane + t * 64;
        if (i < ncand) { CV[wv][i] = WV[cbase + i]; CI[wv][i] = WI[cbase + i]; }
        else           { CV[wv][i] = -INFINITY;     CI[wv][i] = 0x7fffffff;   }
    }
    __syncthreads();

    if (lane == 0) {
        float tv[KTOP]; int ti[KTOP];
#pragma unroll
        for (int j = 0; j < KTOP; ++j) { tv[j] = -INFINITY; ti[j] = 0x7fffffff; }
        for (int i = 0; i < 128; ++i) {
            float s = CV[wv][i];
            if (s == -INFINITY) continue;
            topk_insert(tv, ti, s, CI[wv][i]);
        }
        float mx = tv[0];
        float e[KTOP]; float sum = 0.f;
#pragma unroll
        for (int j = 0; j < KTOP; ++j) {
            e[j] = (tv[j] == -INFINITY) ? 0.f : __expf(tv[j] - mx);
            sum += e[j];
        }
        float inv = 1.f / sum;
#pragma unroll
        for (int j = 0; j < KTOP; ++j) {
            Pp[wv][j] = e[j] * inv;
            Pi[wv][j] = (tv[j] == -INFINITY) ? 0 : ti[j];
        }
    }
    __syncthreads();

    const size_t vbase = (size_t)b * N_ * D_;
#pragma unroll
    for (int it = 0; it < 2; ++it) {
        int c8 = (it * 64 + lane) * 8;
        float o[8];
#pragma unroll
        for (int u = 0; u < 8; ++u) o[u] = 0.f;
#pragma unroll
        for (int j = 0; j < KTOP; ++j) {
            float p = Pp[wv][j];
            ushort4 v0 = *reinterpret_cast<const ushort4*>(
                &V[vbase + (size_t)Pi[wv][j] * D_ + c8]);
            ushort4 v1 = *reinterpret_cast<const ushort4*>(
                &V[vbase + (size_t)Pi[wv][j] * D_ + c8 + 4]);
            o[0] = fmaf(p, uh2f(v0.x), o[0]); o[1] = fmaf(p, uh2f(v0.y), o[1]);
            o[2] = fmaf(p, uh2f(v0.z), o[2]); o[3] = fmaf(p, uh2f(v0.w), o[3]);
            o[4] = fmaf(p, uh2f(v1.x), o[4]); o[5] = fmaf(p, uh2f(v1.y), o[5]);
            o[6] = fmaf(p, uh2f(v1.z), o[6]); o[7] = fmaf(p, uh2f(v1.w), o[7]);
        }
        ushort4 ob0 = {h2u((halfT)o[0]), h2u((halfT)o[1]), h2u((halfT)o[2]), h2u((halfT)o[3])};
        ushort4 ob1 = {h2u((halfT)o[4]), h2u((halfT)o[5]), h2u((halfT)o[6]), h2u((halfT)o[7])};
        *reinterpret_cast<ushort4*>(&CCb[(size_t)rid * 2048 + 1024 + c8]) = ob0;
        *reinterpret_cast<ushort4*>(&CCb[(size_t)rid * 2048 + 1024 + c8 + 4]) = ob1;
    }
}

// ---------------------------------------------------------------------------
extern "C" void kernel_launch(void* const* d_in, const int* in_sizes, int n_in,
                              void* d_out, int out_size, void* d_ws, size_t ws_size,
                              hipStream_t stream)
{
    const float* mu   = (const float*)d_in[0];
    const float* pher = (const float*)d_in[1];
    const float* Wq   = (const float*)d_in[2];
    const float* bq   = (const float*)d_in[3];
    const float* Wk   = (const float*)d_in[4];
    const float* bk   = (const float*)d_in[5];
    const float* Wv   = (const float*)d_in[6];
    const float* bv   = (const float*)d_in[7];
    const float* Wm1  = (const float*)d_in[8];
    const float* bm1  = (const float*)d_in[9];
    const float* Wm2  = (const float*)d_in[10];
    const float* bm2  = (const float*)d_in[11];
    const float* Wo   = (const float*)d_in[12];
    const float* bo   = (const float*)d_in[13];
    float* out = (float*)d_out;
    float* ws  = (float*)d_ws;

    const size_t SZ  = (size_t)B_ * N_ * D_;    // 8388608 floats
    const size_t MEG = 1024 * 1024;             // floats
    const int M = B_ * N_;                      // 8192

    // ---- workspace map (float units), as R13 ----
    ushortT* CCb  = (ushortT*)ws;                         // [8192][2048] fp16
    float*   PF   = ws + SZ;                              // fused pre-act [8192][2048] f32
    ushortT* Qa   = (ushortT*)(ws + SZ);                  // overlay after silu
    ushortT* QB   = Qa + SZ;
    ushortT* Ka   = (ushortT*)(ws + 2 * SZ);
    ushortT* KB   = Ka + SZ;
    ushortT* mu_a = (ushortT*)(ws + 3 * SZ);              // fp16 plane (SZ ushorts)
    ushortT* mu_B = mu_a + SZ;                            // scaled residual plane
    ushortT* Sb   = (ushortT*)(ws + 4 * SZ);              // fp16 S; dead after local gemm
    float*   WVb  = (float*)(ws + 4 * SZ);                // overlay Sb after local gemm
    int*     WIb  = (int*)(WVb + MEG);
    ushortT* Vb16 = (ushortT*)(ws + 4 * SZ + 2 * MEG);    // fp16 V (SZ ushorts)
    ushortT* U    = (ushortT*)(ws + 4 * SZ + 2 * MEG + SZ / 2);   // weights (10M ush)
    ushortT* WtF  = U;                   // [2048][1024] fused Wm1^T = 2M ush
    ushortT* Wt_m2 = U + 2 * MEG;        // [1024][1024] = 1M ush
    ushortT* Wt_v  = U + 3 * MEG;        // 1M ush
    ushortT* WqT_a = U + 4 * MEG;        ushortT* WqT_B = U + 5 * MEG;
    ushortT* WkT_a = U + 6 * MEG;        ushortT* WkT_B = U + 7 * MEG;
    ushortT* Wt_o  = U + 8 * MEG;        // [1024][2048] = 2M ush

    dim3 blk256(256), blk512(512);
    dim3 gD(8, 64);

    // 1. mu -> 2 fp16 planes
    hipLaunchKernelGGL(split2_mu, dim3(SZ / 8 / 128), blk256, 0, stream, mu, mu_a, mu_B);
    // 2. weight transposes. WtF: rows 0..1023 = Wm1_top^T, rows 1024..2047 = Wm1_bot^T
    hipLaunchKernelGGL(transpose_f2h, dim3(32, 32), blk256, 0, stream, Wm1, WtF, 1024, 1024);
    hipLaunchKernelGGL(transpose_f2h, dim3(32, 32), blk256, 0, stream,
                       Wm1 + (size_t)1024 * 1024, WtF + (size_t)1024 * 1024, 1024, 1024);
    hipLaunchKernelGGL(transpose_f2h, dim3(32, 32), blk256, 0, stream, Wm2, Wt_m2, 1024, 1024);
    hipLaunchKernelGGL(transpose_f2h, dim3(32, 32), blk256, 0, stream, Wv, Wt_v, 1024, 1024);
    hipLaunchKernelGGL(transpose_f2h, dim3(64, 32), blk256, 0, stream, Wo, Wt_o, 2048, 1024);
    hipLaunchKernelGGL(transpose_split2, dim3(32, 32), blk256, 0, stream,
                       Wq, WqT_a, WqT_B, 1024, 1024);
    hipLaunchKernelGGL(transpose_split2, dim3(32, 32), blk256, 0, stream,
                       Wk, WkT_a, WkT_B, 1024, 1024);
    // 3. FUSED pre-acts: PF[8192][2048] = mu @ [Wm1_top | Wm1_bot] (no bias)
    hipLaunchKernelGGL((mfma_gemm_h<0>), dim3(16, 64), blk256, 0, stream,
                       mu_a, D_, WtF, D_, (const float*)nullptr, (void*)PF, 2 * D_, D_);
    // 4. silu-mean (adds bm1 inside) -> Sb (fp16)
    hipLaunchKernelGGL(silu_mean, dim3(SZ / 4 / 256), blk256, 0, stream, PF, bm1, Sb);
    // 5. local msgs -> CCb left half (fp16)
    hipLaunchKernelGGL((mfma_gemm_h<1>), gD, blk256, 0, stream,
                       Sb, D_, Wt_m2, D_, bm2, (void*)CCb, 2 * D_, D_);
    // 6. V -> fp16
    hipLaunchKernelGGL((mfma_gemm_h<1>), gD, blk256, 0, stream,
                       mu_a, D_, Wt_v, D_, bv, (void*)Vb16, D_, D_);
    // 7-8. Q/K projections (fp16 split-MFMA, f32-equivalent) -> 2 planes each
    hipLaunchKernelGGL(gemm_split3h, gD, blk512, 0, stream,
                       mu_a, mu_B, WqT_a, WqT_B, bq, Qa, QB);
    hipLaunchKernelGGL(gemm_split3h, gD, blk512, 0, stream,
                       mu_a, mu_B, WkT_a, WkT_B, bk, Ka, KB);
    // 9. scores + per-chunk top-8
    hipLaunchKernelGGL(attn_scores_h, dim3(136, B_), blk512, 0, stream,
                       Qa, QB, Ka, KB, pher, WVb, WIb);
    // 10. merge + softmax + V gather -> CCb right half
    hipLaunchKernelGGL(attn_merge, dim3(M / 4), blk256, 0, stream, WVb, WIb, Vb16, CCb);
    // 11. out = CCb @ Wo + bo (fp16 MFMA, K=2048, f32 out)
    hipLaunchKernelGGL((mfma_gemm_h<0>), gD, blk256, 0, stream,
                       CCb, 2 * D_, Wt_o, 2048, bo, (void*)out, D_, 2 * D_);

    (void)in_sizes; (void)n_in; (void)out_size; (void)ws_size;
}

// Round 18
// 738.377 us; speedup vs baseline: 2.1686x; 1.0259x over previous
//
#include <hip/hip_runtime.h>
#include <hip/hip_bf16.h>
#include <math.h>

#define B_ 4
#define N_ 2048
#define D_ 1024
#define WIN_ 4
#define KTOP 8
#define ALPHA_ 0.3f
#define SCALE_ (1.0f/32.0f)
#define NCH 16          // N_/128 col chunks
#define INV2048 0.00048828125f

typedef unsigned short ushortT;
typedef _Float16 halfT;
typedef __attribute__((ext_vector_type(8))) _Float16 half8v;  // 8 fp16 (4 VGPR)
typedef __attribute__((ext_vector_type(4))) float f32x4;

__device__ inline ushortT h2u(halfT h){ union{halfT h; ushortT u;} x; x.h=h; return x.u; }
__device__ inline halfT  u2h(ushortT u){ union{halfT h; ushortT u;} x; x.u=u; return x.h; }
__device__ inline float  uh2f(ushortT u){ return (float)u2h(u); }

// async global->LDS, 16B per lane (dest = wave-uniform base + lane*16)
__device__ __forceinline__ void gll16(const ushortT* g, ushortT* l) {
    __builtin_amdgcn_global_load_lds(
        (const __attribute__((address_space(1))) void*)g,
        (__attribute__((address_space(3))) void*)l, 16, 0, 0);
}

// ---------------------------------------------------------------------------
// prep_all: ONE launch for all input prep.
//   blocks [0, 8192):      mu f32 -> 2 fp16 planes (a, scaled residual B)
//   blocks [8192, 16384):  weight transposes (7 tasks, 32x32 tiles)
// ---------------------------------------------------------------------------
__global__ __launch_bounds__(256)
void prep_all(const float* __restrict__ mu, const float* __restrict__ Wm1,
              const float* __restrict__ Wm2, const float* __restrict__ Wv,
              const float* __restrict__ Wo, const float* __restrict__ Wq,
              const float* __restrict__ Wk,
              ushortT* __restrict__ mu_a, ushortT* __restrict__ mu_B,
              ushortT* __restrict__ WtF, ushortT* __restrict__ Wt_m2,
              ushortT* __restrict__ Wt_v, ushortT* __restrict__ Wt_o,
              ushortT* __restrict__ WqT_a, ushortT* __restrict__ WqT_B,
              ushortT* __restrict__ WkT_a, ushortT* __restrict__ WkT_B)
{
    const int bid = blockIdx.x;
    if (bid < 8192) {                       // ---- split2_mu ----
        size_t base = ((size_t)bid * 256 + threadIdx.x) * 4;
        float4 v = *reinterpret_cast<const float4*>(&mu[base]);
        float vv[4] = {v.x, v.y, v.z, v.w};
        ushort4 pa, pb;
#pragma unroll
        for (int j = 0; j < 4; ++j) {
            float f = vv[j];
            halfT a = (halfT)f;  float r = f - (float)a;
            halfT b = (halfT)(r * 2048.0f);
            ((ushortT*)&pa)[j] = h2u(a); ((ushortT*)&pb)[j] = h2u(b);
        }
        *reinterpret_cast<ushort4*>(&mu_a[base]) = pa;
        *reinterpret_cast<ushort4*>(&mu_B[base]) = pb;
        return;
    }
    // ---- transposes ----
    __shared__ float t[32][33];
    int b = bid - 8192;
    const float* W; ushortT* Pa; ushortT* Pb = nullptr;
    int K, lb, split = 0;
    if (b < 1024)      { W = Wm1;                       Pa = WtF;                     K = 1024; lb = b; }
    else if (b < 2048) { W = Wm1 + (size_t)1024 * 1024; Pa = WtF + (size_t)1024*1024; K = 1024; lb = b - 1024; }
    else if (b < 3072) { W = Wm2;  Pa = Wt_m2; K = 1024; lb = b - 2048; }
    else if (b < 4096) { W = Wv;   Pa = Wt_v;  K = 1024; lb = b - 3072; }
    else if (b < 6144) { W = Wo;   Pa = Wt_o;  K = 2048; lb = b - 4096; }
    else if (b < 7168) { W = Wq;   Pa = WqT_a; Pb = WqT_B; K = 1024; lb = b - 6144; split = 1; }
    else               { W = Wk;   Pa = WkT_a; Pb = WkT_B; K = 1024; lb = b - 7168; split = 1; }
    const int Nn = 1024;
    const int k0 = (K == 2048) ? (lb & 63) * 32 : (lb & 31) * 32;
    const int n0 = (K == 2048) ? (lb >> 6) * 32 : (lb >> 5) * 32;
    const int tx = threadIdx.x & 31, ty8 = threadIdx.x >> 5;
#pragma unroll
    for (int p = 0; p < 4; ++p) {
        int kk = p * 8 + ty8;
        t[kk][tx] = W[(size_t)(k0 + kk) * Nn + n0 + tx];
    }
    __syncthreads();
#pragma unroll
    for (int p = 0; p < 4; ++p) {
        int nn = p * 8 + ty8;
        float f = t[tx][nn];
        size_t o = (size_t)(n0 + nn) * K + k0 + tx;
        if (split) {
            halfT a = (halfT)f;  float r = f - (float)a;
            halfT bb = (halfT)(r * 2048.0f);
            Pa[o] = h2u(a); Pb[o] = h2u(bb);
        } else {
            Pa[o] = h2u((halfT)f);
        }
    }
}

// ---------------------------------------------------------------------------
// fp16 MFMA GEMM core body (proven): 128x128 tile, BK=64, 4 waves, 64x64/wave.
// ---------------------------------------------------------------------------
__device__ __forceinline__ void gemm_core_h(
    const ushortT* __restrict__ A, int lda, const ushortT* __restrict__ Bt, int ldb,
    const float* __restrict__ bias, void* __restrict__ Cout, int ldc, int K,
    int m0, int n0, int outHalf, ushortT* AsL, ushortT* BsL)
{
    const int tid = threadIdx.x;
    const int w = tid >> 6, lane = tid & 63;
    const int wr = w >> 1, wc = w & 1;

    f32x4 acc[4][4];
#pragma unroll
    for (int mi = 0; mi < 4; ++mi)
#pragma unroll
        for (int ni = 0; ni < 4; ++ni) acc[mi][ni] = (f32x4){0.f, 0.f, 0.f, 0.f};

    for (int k0 = 0; k0 < K; k0 += 64) {
#pragma unroll
        for (int it = 0; it < 4; ++it) {
            int idx = tid + it * 256;        // 0..1023
            int row = idx >> 3, c = idx & 7;
            int4 va = *reinterpret_cast<const int4*>(&A[(size_t)(m0 + row) * lda + k0 + c * 8]);
            *reinterpret_cast<int4*>(&AsL[row * 72 + c * 8]) = va;
            int4 vb = *reinterpret_cast<const int4*>(&Bt[(size_t)(n0 + row) * ldb + k0 + c * 8]);
            *reinterpret_cast<int4*>(&BsL[row * 72 + c * 8]) = vb;
        }
        __syncthreads();
#pragma unroll
        for (int kh = 0; kh < 2; ++kh) {
            const int ko = kh * 32 + (lane >> 4) * 8;
            const int rr = lane & 15;
            half8v af[4], bf[4];
#pragma unroll
            for (int mi = 0; mi < 4; ++mi)
                af[mi] = *reinterpret_cast<const half8v*>(&AsL[(wr * 64 + mi * 16 + rr) * 72 + ko]);
#pragma unroll
            for (int ni = 0; ni < 4; ++ni)
                bf[ni] = *reinterpret_cast<const half8v*>(&BsL[(wc * 64 + ni * 16 + rr) * 72 + ko]);
#pragma unroll
            for (int mi = 0; mi < 4; ++mi)
#pragma unroll
                for (int ni = 0; ni < 4; ++ni)
                    acc[mi][ni] = __builtin_amdgcn_mfma_f32_16x16x32_f16(
                        af[mi], bf[ni], acc[mi][ni], 0, 0, 0);
        }
        __syncthreads();
    }

    const int r4 = (lane >> 4) * 4, cl = lane & 15;
#pragma unroll
    for (int mi = 0; mi < 4; ++mi)
#pragma unroll
        for (int ni = 0; ni < 4; ++ni) {
            int row = m0 + wr * 64 + mi * 16 + r4;
            int col = n0 + wc * 64 + ni * 16 + cl;
            float bb = bias ? bias[col] : 0.f;
#pragma unroll
            for (int r = 0; r < 4; ++r) {
                float v = acc[mi][ni][r] + bb;
                if (outHalf)
                    ((ushortT*)Cout)[(size_t)(row + r) * ldc + col] = h2u((halfT)v);
                else
                    ((float*)Cout)[(size_t)(row + r) * ldc + col] = v;
            }
        }
}

template<int OUT_HALF>
__global__ __launch_bounds__(256)
void mfma_gemm_h(const ushortT* __restrict__ A, int lda,
                 const ushortT* __restrict__ Bt, int ldb,
                 const float* __restrict__ bias,
                 void* __restrict__ Cout, int ldc, int K)
{
    __shared__ ushortT AsL[128 * 72];
    __shared__ ushortT BsL[128 * 72];
    gemm_core_h(A, lda, Bt, ldb, bias, Cout, ldc, K,
                blockIdx.y * 128, blockIdx.x * 128, OUT_HALF, AsL, BsL);
}

// merged: blocks [0,1024) = PF pre-act gemm (Nc=2048, f32 out);
//         blocks [1024,1536) = V gemm (fp16 out)
__global__ __launch_bounds__(256)
void gemm_pf_v(const ushortT* __restrict__ mu_a,
               const ushortT* __restrict__ WtF, const ushortT* __restrict__ Wt_v,
               const float* __restrict__ bv,
               float* __restrict__ PF, ushortT* __restrict__ Vb16)
{
    __shared__ ushortT AsL[128 * 72];
    __shared__ ushortT BsL[128 * 72];
    const int bid = blockIdx.x;
    if (bid < 1024) {
        gemm_core_h(mu_a, D_, WtF, D_, (const float*)nullptr, (void*)PF, 2 * D_, D_,
                    (bid >> 4) * 128, (bid & 15) * 128, 0, AsL, BsL);
    } else {
        const int b2 = bid - 1024;
        gemm_core_h(mu_a, D_, Wt_v, D_, bv, (void*)Vb16, D_, D_,
                    (b2 >> 3) * 128, (b2 & 7) * 128, 1, AsL, BsL);
    }
}

// ---------------------------------------------------------------------------
// Fused pre-act: P is [8192][2048] f32 (cols 0..1023 = self pre-act no bias,
// cols 1024..2047 = neighbor pre-act). S = mean_w silu(P_self + bm1 +
// P_neigh[n-w]), output fp16.
// ---------------------------------------------------------------------------
__global__ __launch_bounds__(256)
void silu_mean(const float* __restrict__ P, const float* __restrict__ bm1,
               ushortT* __restrict__ Sb)
{
    size_t idx4 = (size_t)blockIdx.x * blockDim.x + threadIdx.x;
    size_t base = idx4 << 2;                 // logical [row][1024]
    int row = (int)(base >> 10);
    int col = (int)(base & 1023);
    int n = row & (N_ - 1);
    float4 a = *reinterpret_cast<const float4*>(&P[(size_t)row * 2048 + col]);
    float4 bb = *reinterpret_cast<const float4*>(&bm1[col]);
    a.x += bb.x; a.y += bb.y; a.z += bb.z; a.w += bb.w;
    float sx = 0.f, sy = 0.f, sz = 0.f, sw = 0.f;
#pragma unroll
    for (int w = 1; w <= WIN_; ++w) {
        float xx = a.x, xy = a.y, xz = a.z, xw = a.w;
        if (n >= w) {
            const float4 nb = *reinterpret_cast<const float4*>(
                &P[(size_t)(row - w) * 2048 + 1024 + col]);
            xx += nb.x; xy += nb.y; xz += nb.z; xw += nb.w;
        }
        sx += xx / (1.f + __expf(-xx));
        sy += xy / (1.f + __expf(-xy));
        sz += xz / (1.f + __expf(-xz));
        sw += xw / (1.f + __expf(-xw));
    }
    ushort4 o = {h2u((halfT)(sx * 0.25f)), h2u((halfT)(sy * 0.25f)),
                 h2u((halfT)(sz * 0.25f)), h2u((halfT)(sw * 0.25f))};
    *reinterpret_cast<ushort4*>(&Sb[base]) = o;
}

// ---------------------------------------------------------------------------
__device__ inline void topk_insert(float (&tv)[KTOP], int (&ti)[KTOP], float s, int m)
{
    if ((s > tv[KTOP-1]) || (s == tv[KTOP-1] && m < ti[KTOP-1])) {
        float cs = s; int ci = m;
#pragma unroll
        for (int q = 0; q < KTOP; ++q) {
            bool beats = (cs > tv[q]) || (cs == tv[q] && ci < ti[q]);
            if (beats) { float t0 = tv[q]; int t1 = ti[q];
                         tv[q] = cs; ti[q] = ci; cs = t0; ci = t1; }
        }
    }
}

// ---------------------------------------------------------------------------
// fp16 2-plane 3-product core on gload_lds layout (R15-proven): plane =
// 128 rows x 32 ushorts LINEAR; chunk q of row R at slot q ^ ((R>>1)&3).
// Wave tile 64x32. acc0 += Aa*Ba ; acc1 += Aa*BB + AB*Ba.
// ---------------------------------------------------------------------------
#define SPLIT3H_COMPUTE(Tb, wr, wc, lane, acc0, acc1)                           \
    {                                                                           \
        const int rr_ = (lane) & 15, q_ = (lane) >> 4;                          \
        const int Rb0_ = (wc) * 32 + rr_;                                       \
        const int Rb1_ = Rb0_ + 16;                                             \
        half8v ba0_ = *reinterpret_cast<const half8v*>(                         \
            &Tb[2 * 4096 + Rb0_ * 32 + ((q_ ^ ((Rb0_ >> 1) & 3)) << 3)]);       \
        half8v ba1_ = *reinterpret_cast<const half8v*>(                         \
            &Tb[2 * 4096 + Rb1_ * 32 + ((q_ ^ ((Rb1_ >> 1) & 3)) << 3)]);       \
        half8v bB0_ = *reinterpret_cast<const half8v*>(                         \
            &Tb[3 * 4096 + Rb0_ * 32 + ((q_ ^ ((Rb0_ >> 1) & 3)) << 3)]);       \
        half8v bB1_ = *reinterpret_cast<const half8v*>(                         \
            &Tb[3 * 4096 + Rb1_ * 32 + ((q_ ^ ((Rb1_ >> 1) & 3)) << 3)]);       \
        _Pragma("unroll")                                                       \
        for (int mi_ = 0; mi_ < 4; ++mi_) {                                     \
            const int Ra_ = (wr) * 64 + mi_ * 16 + rr_;                         \
            const int sw_ = (q_ ^ ((Ra_ >> 1) & 3)) << 3;                       \
            half8v aA_ = *reinterpret_cast<const half8v*>(&Tb[Ra_ * 32 + sw_]); \
            acc0[mi_][0] = __builtin_amdgcn_mfma_f32_16x16x32_f16(              \
                aA_, ba0_, acc0[mi_][0], 0, 0, 0);                              \
            acc0[mi_][1] = __builtin_amdgcn_mfma_f32_16x16x32_f16(              \
                aA_, ba1_, acc0[mi_][1], 0, 0, 0);                              \
            acc1[mi_][0] = __builtin_amdgcn_mfma_f32_16x16x32_f16(              \
                aA_, bB0_, acc1[mi_][0], 0, 0, 0);                              \
            acc1[mi_][1] = __builtin_amdgcn_mfma_f32_16x16x32_f16(              \
                aA_, bB1_, acc1[mi_][1], 0, 0, 0);                              \
        }                                                                       \
        _Pragma("unroll")                                                       \
        for (int mi_ = 0; mi_ < 4; ++mi_) {                                     \
            const int Ra_ = (wr) * 64 + mi_ * 16 + rr_;                         \
            const int sw_ = (q_ ^ ((Ra_ >> 1) & 3)) << 3;                       \
            half8v aB_ = *reinterpret_cast<const half8v*>(                      \
                &Tb[4096 + Ra_ * 32 + sw_]);                                    \
            acc1[mi_][0] = __builtin_amdgcn_mfma_f32_16x16x32_f16(              \
                aB_, ba0_, acc1[mi_][0], 0, 0, 0);                              \
            acc1[mi_][1] = __builtin_amdgcn_mfma_f32_16x16x32_f16(              \
                aB_, ba1_, acc1[mi_][1], 0, 0, 0);                              \
        }                                                                       \
    }

// stage one 32-k tile of one plane (this wave's half): 4 x gll16 (1KB each)
#define STAGE4(lb, koff)                                                        \
    {                                                                           \
        gll16(gp + goff + (koff), lb);                                          \
        gll16(gp + goff + (koff) + 16 * D_, (lb) + 512);                        \
        gll16(gp + goff + (koff) + 32 * D_, (lb) + 1024);                       \
        gll16(gp + goff + (koff) + 48 * D_, (lb) + 1536);                       \
    }

// ---------------------------------------------------------------------------
// qk_proj: MERGED Q and K projections. blocks [0,512) = Q, [512,1024) = K.
// out = (Aa + AB/2048) @ (Ba + BB/2048)^T + bias, 3 kept products.
// 512 thr, 8 waves, BK=32, global_load_lds double-buffer, 1 barrier/K-step.
// ---------------------------------------------------------------------------
__global__ __launch_bounds__(512, 2)
void qk_proj(const ushortT* __restrict__ A0, const ushortT* __restrict__ A1,
             const ushortT* __restrict__ QWa, const ushortT* __restrict__ QWB,
             const ushortT* __restrict__ KWa, const ushortT* __restrict__ KWB,
             const float* __restrict__ bq, const float* __restrict__ bk,
             ushortT* __restrict__ Qa, ushortT* __restrict__ QB,
             ushortT* __restrict__ Ka, ushortT* __restrict__ KB)
{
    __shared__ ushortT TT[2][16384];   // 2 x 32KB

    const int half = blockIdx.x >> 9;
    int lin = blockIdx.x & 511;
    lin = (lin & 7) * 64 + (lin >> 3);                    // XCD-chunked
    const int m0 = (lin >> 3) * 128;
    const int n0 = (lin & 7) * 128;

    const ushortT* B0 = half ? KWa : QWa;
    const ushortT* B1 = half ? KWB : QWB;
    const float* bias = half ? bk : bq;
    ushortT* Pa = half ? Ka : Qa;
    ushortT* Pb = half ? KB : QB;

    const int tid = threadIdx.x;
    const int wid = tid >> 6, lane = tid & 63;
    const int wr = wid >> 2, wc = wid & 3;

    const int pl = wid >> 1;
    const int hb = (wid & 1) * 64;
    const ushortT* gp = (pl == 0) ? A0 : (pl == 1) ? A1 : (pl == 2) ? B0 : B1;
    const int rbase = (pl < 2 ? m0 : n0) + hb + (lane >> 2);
    const int cg8 = ((lane & 3) ^ ((lane >> 3) & 3)) << 3;
    const size_t goff = (size_t)rbase * D_ + cg8;
    ushortT* lb0 = &TT[0][pl * 4096 + hb * 32];
    ushortT* lb1 = &TT[1][pl * 4096 + hb * 32];

    f32x4 acc0[4][2], acc1[4][2];
#pragma unroll
    for (int mi = 0; mi < 4; ++mi) {
        acc0[mi][0] = (f32x4){0,0,0,0}; acc0[mi][1] = (f32x4){0,0,0,0};
        acc1[mi][0] = (f32x4){0,0,0,0}; acc1[mi][1] = (f32x4){0,0,0,0};
    }

    STAGE4(lb0, 0)
    __syncthreads();

    int cur = 0;
    for (int ks = 0; ks < 32; ++ks) {
        if (ks < 31) {
            ushortT* lb = cur ? lb0 : lb1;
            STAGE4(lb, (size_t)(ks + 1) * 32)
        }
        const ushortT* Tb = &TT[cur][0];
        __builtin_amdgcn_s_setprio(1);
        SPLIT3H_COMPUTE(Tb, wr, wc, lane, acc0, acc1)
        __builtin_amdgcn_s_setprio(0);
        __syncthreads();
        cur ^= 1;
    }

    const int r4 = (lane >> 4) * 4, cl = lane & 15;
#pragma unroll
    for (int mi = 0; mi < 4; ++mi)
#pragma unroll
        for (int ni = 0; ni < 2; ++ni) {
            int col = n0 + wc * 32 + ni * 16 + cl;
            float bb = bias[col];
#pragma unroll
            for (int r = 0; r < 4; ++r) {
                int row = m0 + wr * 64 + mi * 16 + r4 + r;
                float v = acc0[mi][ni][r] + INV2048 * acc1[mi][ni][r] + bb;
                halfT a = (halfT)v;  float r1 = v - (float)a;
                halfT b = (halfT)(r1 * 2048.0f);
                size_t o = (size_t)row * D_ + col;
                Pa[o] = h2u(a); Pb[o] = h2u(b);
            }
        }
}

// ---------------------------------------------------------------------------
// attn_scores_h: fp16 2-plane split scores + mask + pheromone + per-chunk
// top-8. 512 thr, 8 waves, BK=32, global_load_lds dbuf, 1 barrier/K-step.
// ---------------------------------------------------------------------------
__global__ __launch_bounds__(512, 2)
void attn_scores_h(const ushortT* __restrict__ Qa, const ushortT* __restrict__ QB,
                   const ushortT* __restrict__ Ka, const ushortT* __restrict__ KB,
                   const float* __restrict__ pher,
                   float* __restrict__ WV, int* __restrict__ WI)
{
    __shared__ ushortT TT[2][16384];   // 2 x 32KB
    __shared__ float Ps[128];
    __shared__ float PV[32 * 4 * 8];
    __shared__ int   PI[32 * 4 * 8];
    float* MV = reinterpret_cast<float*>(&TT[0][0]);                 // [32][128]
    int*   MI = reinterpret_cast<int*>((char*)&TT[0][0] + 16384);    // [32][128]

    int lin = blockIdx.y * 136 + blockIdx.x;              // 0..543
    lin = (lin & 7) * 68 + (lin >> 3);                    // XCD-chunked, 544=8*68
    const int b = lin / 136;
    const int xy = lin - b * 136;
    int g = 0;
    while ((g + 1) * (g + 2) / 2 <= xy) ++g;
    const int ch = xy - g * (g + 1) / 2;
    const int n0 = g * 128;
    const int m0 = ch * 128;
    const size_t bN = (size_t)b * N_;

    const int tid = threadIdx.x;
    const int wid = tid >> 6, lane = tid & 63;
    const int wr = wid >> 2, wc = wid & 3;

    if (tid < 128) Ps[tid] = pher[bN + m0 + tid];

    const int pl = wid >> 1;
    const int hb = (wid & 1) * 64;
    const ushortT* gp = (pl == 0) ? Qa : (pl == 1) ? QB : (pl == 2) ? Ka : KB;
    const size_t rbase = bN + (pl < 2 ? n0 : m0) + hb + (lane >> 2);
    const int cg8 = ((lane & 3) ^ ((lane >> 3) & 3)) << 3;
    const size_t goff = rbase * (size_t)D_ + cg8;
    ushortT* lb0 = &TT[0][pl * 4096 + hb * 32];
    ushortT* lb1 = &TT[1][pl * 4096 + hb * 32];

    f32x4 acc0[4][2], acc1[4][2];
#pragma unroll
    for (int mi = 0; mi < 4; ++mi) {
        acc0[mi][0] = (f32x4){0,0,0,0}; acc0[mi][1] = (f32x4){0,0,0,0};
        acc1[mi][0] = (f32x4){0,0,0,0}; acc1[mi][1] = (f32x4){0,0,0,0};
    }

    STAGE4(lb0, 0)
    __syncthreads();

    int cur = 0;
    for (int ks = 0; ks < 32; ++ks) {
        if (ks < 31) {
            ushortT* lb = cur ? lb0 : lb1;
            STAGE4(lb, (size_t)(ks + 1) * 32)
        }
        const ushortT* Tb = &TT[cur][0];
        __builtin_amdgcn_s_setprio(1);
        SPLIT3H_COMPUTE(Tb, wr, wc, lane, acc0, acc1)
        __builtin_amdgcn_s_setprio(0);
        __syncthreads();
        cur ^= 1;
    }

    // ---- fold to per-row top-8: 4 passes of 32 rows ----
    const int r4 = (lane >> 4) * 4, cl = lane & 15;
    for (int p = 0; p < 4; ++p) {
        __syncthreads();                       // TT/MV consumers done
        if (wr == (p >> 1)) {
#pragma unroll
            for (int mi2 = 0; mi2 < 2; ++mi2) {
                const int mi = (p & 1) * 2 + mi2;
#pragma unroll
                for (int ni = 0; ni < 2; ++ni) {
                    int col = wc * 32 + ni * 16 + cl;
                    int m = m0 + col;
#pragma unroll
                    for (int r = 0; r < 4; ++r) {
                        int rloc = mi2 * 16 + r4 + r;
                        int n = n0 + p * 32 + rloc;
                        bool ok = (m <= n);
                        float sc = acc0[mi][ni][r] + INV2048 * acc1[mi][ni][r];
                        MV[rloc * 128 + col] = ok ? (sc * SCALE_ + ALPHA_ * Ps[col])
                                                  : -INFINITY;
                        MI[rloc * 128 + col] = ok ? m : 0x7fffffff;
                    }
                }
            }
        }
        __syncthreads();
        if (tid < 128) {                       // partial top-8 over a 32-col quarter
            const int row = tid >> 2, q4 = tid & 3;
            float tv[KTOP]; int ti[KTOP];
#pragma unroll
            for (int j = 0; j < KTOP; ++j) { tv[j] = -INFINITY; ti[j] = 0x7fffffff; }
            for (int j = 0; j < 32; ++j) {
                float s2 = MV[row * 128 + q4 * 32 + j];
                if (s2 == -INFINITY) continue;
                topk_insert(tv, ti, s2, MI[row * 128 + q4 * 32 + j]);
            }
#pragma unroll
            for (int j = 0; j < KTOP; ++j) {
                PV[(row * 4 + q4) * 8 + j] = tv[j];
                PI[(row * 4 + q4) * 8 + j] = ti[j];
            }
        }
        __syncthreads();
        if (tid < 32) {                        // merge 4 partials -> chunk top-8
            float tv[KTOP]; int ti[KTOP];
#pragma unroll
            for (int j = 0; j < KTOP; ++j) { tv[j] = -INFINITY; ti[j] = 0x7fffffff; }
            for (int i = 0; i < 32; ++i) {
                float s2 = PV[tid * 32 + i];
                if (s2 == -INFINITY) continue;
                topk_insert(tv, ti, s2, PI[tid * 32 + i]);
            }
            int n = n0 + p * 32 + tid;
            size_t base = ((bN + n) * NCH + ch) * 8;
#pragma unroll
            for (int j = 0; j < KTOP; ++j) { WV[base + j] = tv[j]; WI[base + j] = ti[j]; }
        }
    }
}

// ---------------------------------------------------------------------------
// attn_merge: merge <=16 chunk lists -> top-8 -> softmax -> gather fp16 V ->
// CCb right half (fp16). Grid 2048 blocks, 4 rows each.
// ---------------------------------------------------------------------------
__global__ __launch_bounds__(256)
void attn_merge(const float* __restrict__ WV, const int* __restrict__ WI,
                const ushortT* __restrict__ V, ushortT* __restrict__ CCb)
{
    __shared__ float CV[4][128];
    __shared__ int   CI[4][128];
    __shared__ float Pp[4][KTOP];
    __shared__ int   Pi[4][KTOP];

    const int tid  = threadIdx.x;
    const int wv   = tid >> 6;
    const int lane = tid & 63;
    const int rid  = blockIdx.x * 4 + wv;
    const int b    = rid >> 11;
    const int n    = rid & (N_ - 1);
    const int ncand = ((n >> 7) + 1) * 8;
    const size_t cbase = (size_t)rid * (NCH * 8);

#pragma unroll
    for (int t = 0; t < 2; ++t) {
        int i = lane + t * 64;
        if (i < ncand) { CV[wv][i] = WV[cbase + i]; CI[wv][i] = WI[cbase + i]; }
        else           { CV[wv][i] = -INFINITY;     CI[wv][i] = 0x7fffffff;   }
    }
    __syncthreads();

    if (lane == 0) {
        float tv[KTOP]; int ti[KTOP];
#pragma unroll
        for (int j = 0; j < KTOP; ++j) { tv[j] = -INFINITY; ti[j] = 0x7fffffff; }
        for (int i = 0; i < 128; ++i) {
            float s = CV[wv][i];
            if (s == -INFINITY) continue;
            topk_insert(tv, ti, s, CI[wv][i]);
        }
        float mx = tv[0];
        float e[KTOP]; float sum = 0.f;
#pragma unroll
        for (int j = 0; j < KTOP; ++j) {
            e[j] = (tv[j] == -INFINITY) ? 0.f : __expf(tv[j] - mx);
            sum += e[j];
        }
        float inv = 1.f / sum;
#pragma unroll
        for (int j = 0; j < KTOP; ++j) {
            Pp[wv][j] = e[j] * inv;
            Pi[wv][j] = (tv[j] == -INFINITY) ? 0 : ti[j];
        }
    }
    __syncthreads();

    const size_t vbase = (size_t)b * N_ * D_;
#pragma unroll
    for (int it = 0; it < 2; ++it) {
        int c8 = (it * 64 + lane) * 8;
        float o[8];
#pragma unroll
        for (int u = 0; u < 8; ++u) o[u] = 0.f;
#pragma unroll
        for (int j = 0; j < KTOP; ++j) {
            float p = Pp[wv][j];
            ushort4 v0 = *reinterpret_cast<const ushort4*>(
                &V[vbase + (size_t)Pi[wv][j] * D_ + c8]);
            ushort4 v1 = *reinterpret_cast<const ushort4*>(
                &V[vbase + (size_t)Pi[wv][j] * D_ + c8 + 4]);
            o[0] = fmaf(p, uh2f(v0.x), o[0]); o[1] = fmaf(p, uh2f(v0.y), o[1]);
            o[2] = fmaf(p, uh2f(v0.z), o[2]); o[3] = fmaf(p, uh2f(v0.w), o[3]);
            o[4] = fmaf(p, uh2f(v1.x), o[4]); o[5] = fmaf(p, uh2f(v1.y), o[5]);
            o[6] = fmaf(p, uh2f(v1.z), o[6]); o[7] = fmaf(p, uh2f(v1.w), o[7]);
        }
        ushort4 ob0 = {h2u((halfT)o[0]), h2u((halfT)o[1]), h2u((halfT)o[2]), h2u((halfT)o[3])};
        ushort4 ob1 = {h2u((halfT)o[4]), h2u((halfT)o[5]), h2u((halfT)o[6]), h2u((halfT)o[7])};
        *reinterpret_cast<ushort4*>(&CCb[(size_t)rid * 2048 + 1024 + c8]) = ob0;
        *reinterpret_cast<ushort4*>(&CCb[(size_t)rid * 2048 + 1024 + c8 + 4]) = ob1;
    }
}

// ---------------------------------------------------------------------------
extern "C" void kernel_launch(void* const* d_in, const int* in_sizes, int n_in,
                              void* d_out, int out_size, void* d_ws, size_t ws_size,
                              hipStream_t stream)
{
    const float* mu   = (const float*)d_in[0];
    const float* pher = (const float*)d_in[1];
    const float* Wq   = (const float*)d_in[2];
    const float* bq   = (const float*)d_in[3];
    const float* Wk   = (const float*)d_in[4];
    const float* bk   = (const float*)d_in[5];
    const float* Wv   = (const float*)d_in[6];
    const float* bv   = (const float*)d_in[7];
    const float* Wm1  = (const float*)d_in[8];
    const float* bm1  = (const float*)d_in[9];
    const float* Wm2  = (const float*)d_in[10];
    const float* bm2  = (const float*)d_in[11];
    const float* Wo   = (const float*)d_in[12];
    const float* bo   = (const float*)d_in[13];
    float* out = (float*)d_out;
    float* ws  = (float*)d_ws;

    const size_t SZ  = (size_t)B_ * N_ * D_;    // 8388608 floats
    const size_t MEG = 1024 * 1024;             // floats
    const int M = B_ * N_;                      // 8192

    // ---- workspace map (float units). FIXED: Vb16 moved past Sb's full
    // extent (Sb = 4 MEG-floats) so the merged-early V gemm is never
    // clobbered by silu_mean's Sb write. Total = 4SZ + 13MEG = 180 MB.
    ushortT* CCb  = (ushortT*)ws;                         // [8192][2048] fp16 [0,SZ)
    float*   PF   = ws + SZ;                              // [SZ,3SZ) f32 pre-act
    ushortT* Qa   = (ushortT*)(ws + SZ);                  // overlay PF (after silu)
    ushortT* QB   = Qa + SZ;
    ushortT* Ka   = (ushortT*)(ws + 2 * SZ);
    ushortT* KB   = Ka + SZ;
    ushortT* mu_a = (ushortT*)(ws + 3 * SZ);              // [3SZ,3.5SZ)
    ushortT* mu_B = mu_a + SZ;                            // [3.5SZ,4SZ)
    ushortT* Sb   = (ushortT*)(ws + 4 * SZ);              // [4SZ,4SZ+4MEG) fp16 S
    float*   WVb  = (float*)(ws + 4 * SZ);                // overlay Sb (after local gemm)
    int*     WIb  = (int*)(WVb + MEG);
    ushortT* Vb16 = (ushortT*)(ws + 4 * SZ + 4 * MEG);    // [4SZ+4MEG,4SZ+8MEG) — disjoint from Sb
    ushortT* U    = (ushortT*)(ws + 4 * SZ + 8 * MEG);    // weights, 10M ushorts
    ushortT* WtF  = U;                   // [2048][1024] fused Wm1^T = 2M ush
    ushortT* Wt_m2 = U + 2 * MEG;        // [1024][1024] = 1M ush
    ushortT* Wt_v  = U + 3 * MEG;        // 1M ush
    ushortT* WqT_a = U + 4 * MEG;        ushortT* WqT_B = U + 5 * MEG;
    ushortT* WkT_a = U + 6 * MEG;        ushortT* WkT_B = U + 7 * MEG;
    ushortT* Wt_o  = U + 8 * MEG;        // [1024][2048] = 2M ush

    dim3 blk256(256), blk512(512);
    dim3 gD(8, 64);

    // 1. ALL prep: mu split + 7 weight transposes (one launch)
    hipLaunchKernelGGL(prep_all, dim3(16384), blk256, 0, stream,
                       mu, Wm1, Wm2, Wv, Wo, Wq, Wk,
                       mu_a, mu_B, WtF, Wt_m2, Wt_v, Wt_o,
                       WqT_a, WqT_B, WkT_a, WkT_B);
    // 2. PF pre-act gemm + V gemm (merged, 1536 blocks)
    hipLaunchKernelGGL(gemm_pf_v, dim3(1536), blk256, 0, stream,
                       mu_a, WtF, Wt_v, bv, PF, Vb16);
    // 3. silu-mean (consumes PF; adds bm1 inside) -> Sb. PF dead after.
    hipLaunchKernelGGL(silu_mean, dim3(SZ / 4 / 256), blk256, 0, stream, PF, bm1, Sb);
    // 4. local msgs -> CCb left half (consumes Sb)
    hipLaunchKernelGGL((mfma_gemm_h<1>), gD, blk256, 0, stream,
                       Sb, D_, Wt_m2, D_, bm2, (void*)CCb, 2 * D_, D_);
    // 5. Q + K projections (merged; outputs overlay the now-dead PF region)
    hipLaunchKernelGGL(qk_proj, dim3(1024), blk512, 0, stream,
                       mu_a, mu_B, WqT_a, WqT_B, WkT_a, WkT_B,
                       bq, bk, Qa, QB, Ka, KB);
    // 6. scores + per-chunk top-8 (WVb/WIb overlay dead Sb)
    hipLaunchKernelGGL(attn_scores_h, dim3(136, B_), blk512, 0, stream,
                       Qa, QB, Ka, KB, pher, WVb, WIb);
    // 7. merge + softmax + V gather -> CCb right half
    hipLaunchKernelGGL(attn_merge, dim3(M / 4), blk256, 0, stream, WVb, WIb, Vb16, CCb);
    // 8. out = CCb @ Wo + bo (fp16 MFMA, K=2048, f32 out)
    hipLaunchKernelGGL((mfma_gemm_h<0>), gD, blk256, 0, stream,
                       CCb, 2 * D_, Wt_o, 2048, bo, (void*)out, D_, 2 * D_);

    (void)in_sizes; (void)n_in; (void)out_size; (void)ws_size;
}